// Round 1
// 509.086 us; speedup vs baseline: 1.3494x; 1.3494x over previous
//
#include <hip/hip_runtime.h>
#include <cstdint>
#include <cstddef>

#define B_ 8
#define N_ 4096
#define C_ 768
#define H_ 8
#define HD_ 96
#define EPSN 1e-12f

typedef short s16x8 __attribute__((ext_vector_type(8)));   // 8 bf16 (4 VGPRs)
typedef short s16x4 __attribute__((ext_vector_type(4)));
typedef float f32x4 __attribute__((ext_vector_type(4)));   // MFMA acc

// fp32 -> bf16 (RNE) as raw short bits
static __device__ __forceinline__ short f2bf(float f) {
  unsigned u = __float_as_uint(f);
  unsigned r = (u + 0x7fff + ((u >> 16) & 1)) >> 16;
  return (short)r;
}
static __device__ __forceinline__ float bf2f(unsigned short s) {
  return __uint_as_float(((unsigned)s) << 16);
}
static __device__ __forceinline__ s16x8 pack8(const float4 a, const float4 b) {
  s16x8 r;
  r[0] = f2bf(a.x); r[1] = f2bf(a.y); r[2] = f2bf(a.z); r[3] = f2bf(a.w);
  r[4] = f2bf(b.x); r[5] = f2bf(b.y); r[6] = f2bf(b.z); r[7] = f2bf(b.w);
  return r;
}

// token-index swizzle for transposed LDS staging: XOR the 8-token block index
// with low bits of (ch>>2) so the 4-token s16x4 writes spread across banks.
#define TSW(ch, t) ((t) ^ ((((ch) >> 2) & 7) << 3))

// ---------------------------------------------------------------------------
// gram: G[b] = X_b^T X_b (768x768, bf16), symmetric-pair blocks (tj >= ti).
// 128x128 tile, BK=64 tokens, 4 waves 2x2, each wave 4x4 16x16x32 frags.
// X staged transposed ([channel][token]) in LDS; diag blocks stage once.
// ---------------------------------------------------------------------------
__global__ __launch_bounds__(256)
void gram(const float* __restrict__ x, short* __restrict__ G) {
  int rem = blockIdx.x, ti = 0;
#pragma unroll
  for (int it = 0; it < 5; ++it)
    if (rem >= 6 - ti) { rem -= 6 - ti; ++ti; }
  const int tj = ti + rem;
  const int b = blockIdx.y;
  const int i0 = ti * 128, j0 = tj * 128;
  const bool diag = (ti == tj);

  const int tid = threadIdx.x;
  const int lane = tid & 63, wave = tid >> 6;
  const int l15 = lane & 15, quad = lane >> 4;
  const int wm = wave & 1, wn = wave >> 1;

  __shared__ __align__(16) short smem[2 * 128 * 72];   // 36864 B
  short* At = smem;
  short* Bt = smem + 128 * 72;

  const int tg = tid >> 4;       // 0..15 -> t0 = 4*tg
  const int cg = tid & 15;       // 0..15 -> c0 = 4*cg (and +64)
  const int t0 = tg * 4;
  const int c0 = cg * 4;
  const float* xb = x + (size_t)b * N_ * C_;

  f32x4 acc[4][4] = {};

  for (int n0 = 0; n0 < N_; n0 += 64) {
    float4 la[2][4], lb[2][4];
#pragma unroll
    for (int q = 0; q < 2; ++q)
#pragma unroll
      for (int r = 0; r < 4; ++r)
        la[q][r] = *(const float4*)(xb + (size_t)(n0 + t0 + r) * C_ + i0 + c0 + q * 64);
    if (!diag) {
#pragma unroll
      for (int q = 0; q < 2; ++q)
#pragma unroll
        for (int r = 0; r < 4; ++r)
          lb[q][r] = *(const float4*)(xb + (size_t)(n0 + t0 + r) * C_ + j0 + c0 + q * 64);
    }
    __syncthreads();
#pragma unroll
    for (int q = 0; q < 2; ++q)
#pragma unroll
      for (int cc = 0; cc < 4; ++cc) {
        const int ch = c0 + q * 64 + cc;
        s16x4 v;
        v[0] = f2bf(((const float*)&la[q][0])[cc]);
        v[1] = f2bf(((const float*)&la[q][1])[cc]);
        v[2] = f2bf(((const float*)&la[q][2])[cc]);
        v[3] = f2bf(((const float*)&la[q][3])[cc]);
        *(s16x4*)&At[ch * 72 + TSW(ch, t0)] = v;
      }
    if (!diag) {
#pragma unroll
      for (int q = 0; q < 2; ++q)
#pragma unroll
        for (int cc = 0; cc < 4; ++cc) {
          const int ch = c0 + q * 64 + cc;
          s16x4 v;
          v[0] = f2bf(((const float*)&lb[q][0])[cc]);
          v[1] = f2bf(((const float*)&lb[q][1])[cc]);
          v[2] = f2bf(((const float*)&lb[q][2])[cc]);
          v[3] = f2bf(((const float*)&lb[q][3])[cc]);
          *(s16x4*)&Bt[ch * 72 + TSW(ch, t0)] = v;
        }
    }
    __syncthreads();
    const short* Bre = diag ? At : Bt;
#pragma unroll
    for (int ks = 0; ks < 64; ks += 32) {
      s16x8 af[4], bfr[4];
#pragma unroll
      for (int mi = 0; mi < 4; ++mi) {
        const int ch = wm * 64 + mi * 16 + l15;
        af[mi] = *(const s16x8*)&At[ch * 72 + TSW(ch, ks + quad * 8)];
      }
#pragma unroll
      for (int ni = 0; ni < 4; ++ni) {
        const int ch = wn * 64 + ni * 16 + l15;
        bfr[ni] = *(const s16x8*)&Bre[ch * 72 + TSW(ch, ks + quad * 8)];
      }
#pragma unroll
      for (int ni = 0; ni < 4; ++ni)
#pragma unroll
        for (int mi = 0; mi < 4; ++mi)
          acc[mi][ni] = __builtin_amdgcn_mfma_f32_16x16x32_bf16(af[mi], bfr[ni], acc[mi][ni], 0, 0, 0);
    }
  }

  short* Gb = G + (size_t)b * C_ * C_;
  // direct tile: row i (= quad*4+r within frag), col j (= l15)
#pragma unroll
  for (int mi = 0; mi < 4; ++mi)
#pragma unroll
    for (int ni = 0; ni < 4; ++ni) {
      const int ii = wm * 64 + mi * 16 + quad * 4;
      const int jj = wn * 64 + ni * 16 + l15;
#pragma unroll
      for (int r = 0; r < 4; ++r)
        Gb[(size_t)(i0 + ii + r) * C_ + j0 + jj] = f2bf(acc[mi][ni][r]);
    }
  if (!diag) {
    // transposed mirror tile via LDS for coalesced stores
    __syncthreads();
    short* Ts = smem;   // 128*136 = 17408 shorts <= 18432
#pragma unroll
    for (int mi = 0; mi < 4; ++mi)
#pragma unroll
      for (int ni = 0; ni < 4; ++ni) {
        const int ii = wm * 64 + mi * 16 + quad * 4;
        const int jj = wn * 64 + ni * 16 + l15;
#pragma unroll
        for (int r = 0; r < 4; ++r)
          Ts[jj * 136 + ii + r] = f2bf(acc[mi][ni][r]);
      }
    __syncthreads();
#pragma unroll
    for (int p = 0; p < 8; ++p) {
      const int id = tid + p * 256;     // 0..2047
      const int j = id >> 4, cs = (id & 15) * 8;
      *(s16x8*)&Gb[(size_t)(j0 + j) * C_ + i0 + cs] = *(const s16x8*)&Ts[j * 136 + cs];
    }
  }
}

// ---------------------------------------------------------------------------
// gemm_fb: Out[z][m][n] (bf16) = sum_k A[m][k] (fp32) * Bb[z][n][k] (bf16).
// NT-form MFMA GEMM (B operand given row-major over k). 128x128 tile, BK=32.
// Used for: Y = W_qk @ G   (G symmetric => G[n][k] == G[k][n])
//           Mb = w_proj @ AV (via AV^T stored row-major)
// ---------------------------------------------------------------------------
__global__ __launch_bounds__(256)
void gemm_fb(const float* __restrict__ A, const short* __restrict__ Bb,
             short* __restrict__ Out, size_t sB, size_t sO) {
  const int z = blockIdx.z;
  const int n0 = blockIdx.x * 128;
  const int m0 = blockIdx.y * 128;
  const int tid = threadIdx.x;
  const int lane = tid & 63, wave = tid >> 6;
  const int l15 = lane & 15, quad = lane >> 4;
  const int wm = wave & 1, wn = wave >> 1;

  __shared__ __align__(16) short As[128 * 40];
  __shared__ __align__(16) short Bs[128 * 40];

  const int ar = tid >> 1;
  const int ak = (tid & 1) * 16;
  const float* ap = A + (size_t)(m0 + ar) * C_ + ak;
  const short* bp = Bb + (size_t)z * sB + (size_t)(n0 + ar) * C_ + ak;

  f32x4 acc[4][4] = {};

  for (int k0 = 0; k0 < C_; k0 += 32) {
    const float4 a0 = *(const float4*)(ap + k0 + 0);
    const float4 a1 = *(const float4*)(ap + k0 + 4);
    const float4 a2 = *(const float4*)(ap + k0 + 8);
    const float4 a3 = *(const float4*)(ap + k0 + 12);
    const s16x8 b0 = *(const s16x8*)(bp + k0 + 0);
    const s16x8 b1 = *(const s16x8*)(bp + k0 + 8);
    __syncthreads();
    *(s16x8*)&As[ar * 40 + ak]     = pack8(a0, a1);
    *(s16x8*)&As[ar * 40 + ak + 8] = pack8(a2, a3);
    *(s16x8*)&Bs[ar * 40 + ak]     = b0;
    *(s16x8*)&Bs[ar * 40 + ak + 8] = b1;
    __syncthreads();
    s16x8 af[4];
#pragma unroll
    for (int mi = 0; mi < 4; ++mi)
      af[mi] = *(const s16x8*)&As[(wm * 64 + mi * 16 + l15) * 40 + quad * 8];
#pragma unroll
    for (int ni = 0; ni < 4; ++ni) {
      const s16x8 bf = *(const s16x8*)&Bs[(wn * 64 + ni * 16 + l15) * 40 + quad * 8];
#pragma unroll
      for (int mi = 0; mi < 4; ++mi)
        acc[mi][ni] = __builtin_amdgcn_mfma_f32_16x16x32_bf16(af[mi], bf, acc[mi][ni], 0, 0, 0);
    }
  }

  short* ob = Out + (size_t)z * sO;
#pragma unroll
  for (int mi = 0; mi < 4; ++mi) {
    const int m = m0 + wm * 64 + mi * 16 + quad * 4;
#pragma unroll
    for (int ni = 0; ni < 4; ++ni) {
      const int n = n0 + wn * 64 + ni * 16 + l15;
#pragma unroll
      for (int r = 0; r < 4; ++r)
        ob[(size_t)(m + r) * C_ + n] = f2bf(acc[mi][ni][r]);
    }
  }
}

// ---------------------------------------------------------------------------
// row_norms: norms for q (first 768 rows of Y) and k (next 768) per batch.
// ||q_d||^2 = dot(Y[row], w_qkv[row]) since Y = W_qk G, G = X^T X.
// One wave per row.
// ---------------------------------------------------------------------------
__global__ __launch_bounds__(256)
void row_norms(const short* __restrict__ Y, const float* __restrict__ w_qkv,
               float* __restrict__ norms) {
  const int b = blockIdx.y;
  const int m = blockIdx.x * 4 + (threadIdx.x >> 6);   // 0..1535
  const int lane = threadIdx.x & 63;
  const short* y = Y + ((size_t)b * 1536 + m) * C_;
  const float* w = w_qkv + (size_t)m * C_;
  float s = 0.f;
#pragma unroll
  for (int j = 0; j < 3; ++j) {
    const int o = j * 256 + lane * 4;
    const s16x4 yv = *(const s16x4*)(y + o);
    const float4 wv = *(const float4*)(w + o);
    s += bf2f((unsigned short)yv[0]) * wv.x + bf2f((unsigned short)yv[1]) * wv.y +
         bf2f((unsigned short)yv[2]) * wv.z + bf2f((unsigned short)yv[3]) * wv.w;
  }
#pragma unroll
  for (int o = 32; o > 0; o >>= 1) s += __shfl_xor(s, o);
  if (lane == 0) {
    int idx;
    if (m < 768) idx = (b * 8 + m / 96) * 96 + (m % 96);
    else { const int mm = m - 768; idx = B_ * H_ * 96 + (b * 8 + mm / 96) * 96 + (mm % 96); }
    norms[idx] = s;
  }
}

// ---------------------------------------------------------------------------
// s_attn: per (b,h): S_raw = Yq_h @ Wk_h^T via MFMA (K=768), scale by
// temperature / (|q_d| |k_e|), row softmax, store attn (fp32) to S.
// ---------------------------------------------------------------------------
__global__ __launch_bounds__(256)
void s_attn(const short* __restrict__ Y, const float* __restrict__ w_qkv,
            const float* __restrict__ norms, const float* __restrict__ temp,
            float* __restrict__ S) {
  const int bh = blockIdx.x;
  const int b = bh >> 3, h = bh & 7;
  const int tid = threadIdx.x;
  const int lane = tid & 63, wave = tid >> 6;
  const int l15 = lane & 15, quad = lane >> 4;

  __shared__ __align__(16) float Sf[96 * 97];   // 37248 B; aliased as bf16 staging
  __shared__ float qsc[96], ksc[96];
  short* Ys = (short*)Sf;                // 96*72 shorts
  short* Ks = (short*)Sf + 96 * 72;      // 96*72 shorts (27648 B total)

  if (tid < 96)
    qsc[tid] = temp[h] / fmaxf(sqrtf(norms[bh * 96 + tid]), EPSN);
  else if (tid < 192)
    ksc[tid - 96] = 1.0f / fmaxf(sqrtf(norms[B_ * H_ * 96 + bh * 96 + (tid - 96)]), EPSN);

  const short* yb = Y + ((size_t)b * 1536 + h * 96) * C_;
  const float* wk = w_qkv + (size_t)(C_ + h * 96) * C_;

  f32x4 sc[9] = {};
  for (int k0 = 0; k0 < C_; k0 += 64) {
    s16x8 yv[3];
    float4 wv[3][2];
#pragma unroll
    for (int j = 0; j < 3; ++j) {
      const int id = tid + j * 256;           // 0..767
      const int r = id >> 3, c8 = (id & 7) * 8;
      yv[j] = *(const s16x8*)(yb + (size_t)r * C_ + k0 + c8);
      wv[j][0] = *(const float4*)(wk + (size_t)r * C_ + k0 + c8);
      wv[j][1] = *(const float4*)(wk + (size_t)r * C_ + k0 + c8 + 4);
    }
    __syncthreads();
#pragma unroll
    for (int j = 0; j < 3; ++j) {
      const int id = tid + j * 256;
      const int r = id >> 3, c8 = (id & 7) * 8;
      *(s16x8*)&Ys[r * 72 + c8] = yv[j];
      *(s16x8*)&Ks[r * 72 + c8] = pack8(wv[j][0], wv[j][1]);
    }
    __syncthreads();
#pragma unroll
    for (int j = 0; j < 9; ++j) {
      const int t = wave * 9 + j, dt = t / 6, et = t % 6;
#pragma unroll
      for (int kk = 0; kk < 64; kk += 32) {
        const s16x8 a  = *(const s16x8*)&Ys[(dt * 16 + l15) * 72 + kk + quad * 8];
        const s16x8 bb = *(const s16x8*)&Ks[(et * 16 + l15) * 72 + kk + quad * 8];
        sc[j] = __builtin_amdgcn_mfma_f32_16x16x32_bf16(a, bb, sc[j], 0, 0, 0);
      }
    }
  }
  __syncthreads();
#pragma unroll
  for (int j = 0; j < 9; ++j) {
    const int t = wave * 9 + j, dt = t / 6, et = t % 6;
    const int e = et * 16 + l15;
    const float kf = ksc[e];
#pragma unroll
    for (int r = 0; r < 4; ++r) {
      const int d = dt * 16 + quad * 4 + r;
      Sf[d * 97 + e] = sc[j][r] * qsc[d] * kf;
    }
  }
  __syncthreads();
  float* Sb = S + (size_t)bh * (HD_ * HD_);
  for (int rr = 0; rr < 24; ++rr) {
    const int d = wave * 24 + rr;
    const float v0 = Sf[d * 97 + lane];
    const float v1 = (lane < 32) ? Sf[d * 97 + 64 + lane] : -1e30f;
    float mx = fmaxf(v0, v1);
#pragma unroll
    for (int o = 32; o > 0; o >>= 1) mx = fmaxf(mx, __shfl_xor(mx, o));
    const float e0 = __expf(v0 - mx);
    const float e1 = (lane < 32) ? __expf(v1 - mx) : 0.0f;
    float sum = e0 + e1;
#pragma unroll
    for (int o = 32; o > 0; o >>= 1) sum += __shfl_xor(sum, o);
    const float inv = 1.0f / sum;
    Sb[d * 96 + lane] = e0 * inv;
    if (lane < 32) Sb[d * 96 + 64 + lane] = e1 * inv;
  }
}

// ---------------------------------------------------------------------------
// av_gemm: AVt[b][c][h*96+d] (bf16) = sum_e attn[bh][d][e] * w_qkv[2C+h*96+e][c]
// (transposed + bf16 output so the w_proj GEMM can run as NT MFMA)
// ---------------------------------------------------------------------------
__global__ __launch_bounds__(256)
void av_gemm(const float* __restrict__ S, const float* __restrict__ w_qkv,
             short* __restrict__ AVt) {
  const int bh = blockIdx.x;
  const int b = bh >> 3, h = bh & 7;
  const int ct = blockIdx.y * 64;
  const int tid = threadIdx.x;
  __shared__ float at[96 * 97];
  __shared__ float wv[96 * 64];
  const float* Sb = S + (size_t)bh * (HD_ * HD_);
  for (int i = tid; i < 96 * 96; i += 256)
    at[(i / 96) * 97 + (i % 96)] = Sb[i];
  for (int i = tid; i < 96 * 64; i += 256) {
    const int e = i >> 6, c = i & 63;
    wv[e * 64 + c] = w_qkv[(size_t)(2 * C_ + h * 96 + e) * C_ + ct + c];
  }
  __syncthreads();
  const int d0 = (tid >> 4) * 6;
  const int c0 = (tid & 15) * 4;
  float acc[6][4] = {};
  for (int e = 0; e < 96; ++e) {
    const float4 bv = *(const float4*)&wv[e * 64 + c0];
    float aa[6];
#pragma unroll
    for (int i = 0; i < 6; ++i) aa[i] = at[(d0 + i) * 97 + e];
#pragma unroll
    for (int i = 0; i < 6; ++i) {
      acc[i][0] += aa[i] * bv.x; acc[i][1] += aa[i] * bv.y;
      acc[i][2] += aa[i] * bv.z; acc[i][3] += aa[i] * bv.w;
    }
  }
  short* AVb = AVt + (size_t)b * C_ * C_;
#pragma unroll
  for (int i = 0; i < 6; ++i)
#pragma unroll
    for (int j = 0; j < 4; ++j)
      AVb[(size_t)(ct + c0 + j) * C_ + h * 96 + d0 + i] = f2bf(acc[i][j]);
}

// ---------------------------------------------------------------------------
// Final GEMM via bf16 MFMA: out[z][m][n] = sum_k x[z][m][k]*Mb[z][n][k] + bias[n]
// (unchanged)
// ---------------------------------------------------------------------------
__global__ __launch_bounds__(256)
void gemm_xm(const float* __restrict__ x, const short* __restrict__ Mb,
             const float* __restrict__ bias, float* __restrict__ out) {
  const int z = blockIdx.z;
  const int n0 = blockIdx.x * 128;
  const int m0 = blockIdx.y * 128;
  const int tid = threadIdx.x;
  const int lane = tid & 63;
  const int wave = tid >> 6;
  const int l15 = lane & 15;
  const int quad = lane >> 4;
  const int wm = wave & 1;
  const int wn = wave >> 1;

  __shared__ __align__(16) short As[128 * 40];
  __shared__ __align__(16) short Bs[128 * 40];

  const int ar = tid >> 1;
  const int ak = (tid & 1) * 16;
  const float* xp = x + ((size_t)z * N_ + m0 + ar) * C_ + ak;
  const short* mp = Mb + (size_t)z * C_ * C_ + (size_t)(n0 + ar) * C_ + ak;

  f32x4 acc[4][4] = {};

  for (int k0 = 0; k0 < C_; k0 += 32) {
    const float4 a0 = *(const float4*)(xp + k0 + 0);
    const float4 a1 = *(const float4*)(xp + k0 + 4);
    const float4 a2 = *(const float4*)(xp + k0 + 8);
    const float4 a3 = *(const float4*)(xp + k0 + 12);
    const s16x8 b0 = *(const s16x8*)(mp + k0 + 0);
    const s16x8 b1 = *(const s16x8*)(mp + k0 + 8);
    __syncthreads();
    *(s16x8*)&As[ar * 40 + ak]     = pack8(a0, a1);
    *(s16x8*)&As[ar * 40 + ak + 8] = pack8(a2, a3);
    *(s16x8*)&Bs[ar * 40 + ak]     = b0;
    *(s16x8*)&Bs[ar * 40 + ak + 8] = b1;
    __syncthreads();
    s16x8 af[4];
#pragma unroll
    for (int mi = 0; mi < 4; ++mi)
      af[mi] = *(const s16x8*)&As[(wm * 64 + mi * 16 + l15) * 40 + quad * 8];
#pragma unroll
    for (int ni = 0; ni < 4; ++ni) {
      const s16x8 bf = *(const s16x8*)&Bs[(wn * 64 + ni * 16 + l15) * 40 + quad * 8];
#pragma unroll
      for (int mi = 0; mi < 4; ++mi)
        acc[mi][ni] = __builtin_amdgcn_mfma_f32_16x16x32_bf16(af[mi], bf, acc[mi][ni], 0, 0, 0);
    }
  }

  float bv[4];
#pragma unroll
  for (int ni = 0; ni < 4; ++ni) bv[ni] = bias[n0 + wn * 64 + ni * 16 + l15];
#pragma unroll
  for (int mi = 0; mi < 4; ++mi) {
    const int m = m0 + wm * 64 + mi * 16 + quad * 4;
#pragma unroll
    for (int ni = 0; ni < 4; ++ni) {
      const int n = n0 + wn * 64 + ni * 16 + l15;
      float* dst = out + ((size_t)z * N_ + m) * C_ + n;
#pragma unroll
      for (int r = 0; r < 4; ++r)
        dst[(size_t)r * C_] = acc[mi][ni][r] + bv[ni];
    }
  }
}

// ---------------------------------------------------------------------------
extern "C" void kernel_launch(void* const* d_in, const int* in_sizes, int n_in,
                              void* d_out, int out_size, void* d_ws, size_t ws_size,
                              hipStream_t stream) {
  const float* x      = (const float*)d_in[0];
  const float* w_qkv  = (const float*)d_in[1];
  const float* temp   = (const float*)d_in[2];
  const float* w_proj = (const float*)d_in[3];
  const float* b_proj = (const float*)d_in[4];
  float* out = (float*)d_out;

  // workspace layout (~47.3 MiB):
  //   S     : 589824 f   (attn, fp32)
  //   norms : 12288 f    (q then k)
  //   big   : 4718592 f  region -> G (bf16, 9.4MB) then reused as AVt (bf16)
  //   Mb    : 4718592 bf16
  //   Y     : 9437184 bf16  (W_qk @ G, per batch 1536x768)
  float* ws    = (float*)d_ws;
  float* S     = ws;
  float* norms = S + (size_t)B_ * H_ * HD_ * HD_;
  float* big   = norms + 2 * B_ * H_ * HD_;
  short* G     = (short*)big;                       // dead after gemm_fb(Y)
  short* AVt   = (short*)big;                       // written by av_gemm later
  short* Mb    = (short*)(big + (size_t)B_ * C_ * C_);
  short* Y     = Mb + (size_t)B_ * C_ * C_;

  // G_b = X_b^T X_b  (symmetric pairs, both triangles written)
  gram<<<dim3(21, B_), 256, 0, stream>>>(x, G);

  // Y_b = W_qk @ G_b   (G symmetric -> NT form)
  gemm_fb<<<dim3(C_ / 128, 1536 / 128, B_), 256, 0, stream>>>(
      w_qkv, G, Y, (size_t)C_ * C_, (size_t)1536 * C_);

  // per-row norms: ||q_d||^2 = dot(Y row, W row)
  row_norms<<<dim3(1536 / 4, B_), 256, 0, stream>>>(Y, w_qkv, norms);

  // S = softmax( temp * Yq Wk^T / (|q||k|) )  per (b,h)
  s_attn<<<B_ * H_, 256, 0, stream>>>(Y, w_qkv, norms, temp, S);

  // AVt_b[c][vchan] = (attn @ W_v)^T  (bf16)
  av_gemm<<<dim3(B_ * H_, C_ / 64), 256, 0, stream>>>(S, w_qkv, AVt);

  // Mb_z = bf16( w_proj @ AV_z )  stored [cout][cin]  (NT MFMA via AVt)
  gemm_fb<<<dim3(C_ / 128, C_ / 128, B_), 256, 0, stream>>>(
      w_proj, AVt, Mb, (size_t)C_ * C_, (size_t)C_ * C_);

  // out[z] = x[z] @ Mb_z^T + bias  (bf16 MFMA)
  gemm_xm<<<dim3(C_ / 128, N_ / 128, B_), 256, 0, stream>>>(x, Mb, b_proj, out);
}

// Round 2
// 490.883 us; speedup vs baseline: 1.3994x; 1.0371x over previous
//
#include <hip/hip_runtime.h>
#include <cstdint>
#include <cstddef>

#define B_ 8
#define N_ 4096
#define C_ 768
#define H_ 8
#define HD_ 96
#define EPSN 1e-12f
#define NS_ 4          // gram split-K factor over tokens

typedef short s16x8 __attribute__((ext_vector_type(8)));   // 8 bf16 (4 VGPRs)
typedef short s16x4 __attribute__((ext_vector_type(4)));
typedef float f32x4 __attribute__((ext_vector_type(4)));   // MFMA acc

// fp32 -> bf16 (RNE) as raw short bits
static __device__ __forceinline__ short f2bf(float f) {
  unsigned u = __float_as_uint(f);
  unsigned r = (u + 0x7fff + ((u >> 16) & 1)) >> 16;
  return (short)r;
}
static __device__ __forceinline__ float bf2f(unsigned short s) {
  return __uint_as_float(((unsigned)s) << 16);
}
static __device__ __forceinline__ s16x8 pack8(const float4 a, const float4 b) {
  s16x8 r;
  r[0] = f2bf(a.x); r[1] = f2bf(a.y); r[2] = f2bf(a.z); r[3] = f2bf(a.w);
  r[4] = f2bf(b.x); r[5] = f2bf(b.y); r[6] = f2bf(b.z); r[7] = f2bf(b.w);
  return r;
}

// token-index swizzle for transposed LDS staging: XOR the 8-token block index
// with low bits of (ch>>2) so the 4-token s16x4 writes spread across banks.
#define TSW(ch, t) ((t) ^ ((((ch) >> 2) & 7) << 3))

// ---------------------------------------------------------------------------
// gram_p: partial Gram. For pair tile (ti,tj) and token chunk s:
//   Gp[((b*21+pair)*NS+s)] (128x128 fp32) = sum_{n in chunk} X[n,i0+:]^T X[n,j0+:]
// Split-K over tokens fixes the 168-block occupancy starvation (was 7% occ).
// ---------------------------------------------------------------------------
__global__ __launch_bounds__(256)
void gram_p(const float* __restrict__ x, float* __restrict__ Gp) {
  const int pair = blockIdx.x;
  int rem = pair, ti = 0;
#pragma unroll
  for (int it = 0; it < 5; ++it)
    if (rem >= 6 - ti) { rem -= 6 - ti; ++ti; }
  const int tj = ti + rem;
  const int split = blockIdx.y;
  const int b = blockIdx.z;
  const int i0 = ti * 128, j0 = tj * 128;
  const bool diag = (ti == tj);

  const int tid = threadIdx.x;
  const int lane = tid & 63, wave = tid >> 6;
  const int l15 = lane & 15, quad = lane >> 4;
  const int wm = wave & 1, wn = wave >> 1;

  __shared__ __align__(16) short smem[2 * 128 * 72];   // 36864 B
  short* At = smem;
  short* Bt = smem + 128 * 72;

  const int tg = tid >> 4;       // 0..15 -> t0 = 4*tg
  const int cg = tid & 15;       // 0..15 -> c0 = 4*cg (and +64)
  const int t0 = tg * 4;
  const int c0 = cg * 4;
  const float* xb = x + (size_t)b * N_ * C_;

  f32x4 acc[4][4] = {};

  const int nbeg = split * (N_ / NS_);
  const int nend = nbeg + (N_ / NS_);
  for (int n0 = nbeg; n0 < nend; n0 += 64) {
    float4 la[2][4], lb[2][4];
#pragma unroll
    for (int q = 0; q < 2; ++q)
#pragma unroll
      for (int r = 0; r < 4; ++r)
        la[q][r] = *(const float4*)(xb + (size_t)(n0 + t0 + r) * C_ + i0 + c0 + q * 64);
    if (!diag) {
#pragma unroll
      for (int q = 0; q < 2; ++q)
#pragma unroll
        for (int r = 0; r < 4; ++r)
          lb[q][r] = *(const float4*)(xb + (size_t)(n0 + t0 + r) * C_ + j0 + c0 + q * 64);
    }
    __syncthreads();
#pragma unroll
    for (int q = 0; q < 2; ++q)
#pragma unroll
      for (int cc = 0; cc < 4; ++cc) {
        const int ch = c0 + q * 64 + cc;
        s16x4 v;
        v[0] = f2bf(((const float*)&la[q][0])[cc]);
        v[1] = f2bf(((const float*)&la[q][1])[cc]);
        v[2] = f2bf(((const float*)&la[q][2])[cc]);
        v[3] = f2bf(((const float*)&la[q][3])[cc]);
        *(s16x4*)&At[ch * 72 + TSW(ch, t0)] = v;
      }
    if (!diag) {
#pragma unroll
      for (int q = 0; q < 2; ++q)
#pragma unroll
        for (int cc = 0; cc < 4; ++cc) {
          const int ch = c0 + q * 64 + cc;
          s16x4 v;
          v[0] = f2bf(((const float*)&lb[q][0])[cc]);
          v[1] = f2bf(((const float*)&lb[q][1])[cc]);
          v[2] = f2bf(((const float*)&lb[q][2])[cc]);
          v[3] = f2bf(((const float*)&lb[q][3])[cc]);
          *(s16x4*)&Bt[ch * 72 + TSW(ch, t0)] = v;
        }
    }
    __syncthreads();
    const short* Bre = diag ? At : Bt;
#pragma unroll
    for (int ks = 0; ks < 64; ks += 32) {
      s16x8 af[4], bfr[4];
#pragma unroll
      for (int mi = 0; mi < 4; ++mi) {
        const int ch = wm * 64 + mi * 16 + l15;
        af[mi] = *(const s16x8*)&At[ch * 72 + TSW(ch, ks + quad * 8)];
      }
#pragma unroll
      for (int ni = 0; ni < 4; ++ni) {
        const int ch = wn * 64 + ni * 16 + l15;
        bfr[ni] = *(const s16x8*)&Bre[ch * 72 + TSW(ch, ks + quad * 8)];
      }
#pragma unroll
      for (int ni = 0; ni < 4; ++ni)
#pragma unroll
        for (int mi = 0; mi < 4; ++mi)
          acc[mi][ni] = __builtin_amdgcn_mfma_f32_16x16x32_bf16(af[mi], bfr[ni], acc[mi][ni], 0, 0, 0);
    }
  }

  float* Gpb = Gp + (((size_t)b * 21 + pair) * NS_ + split) * (128 * 128);
#pragma unroll
  for (int mi = 0; mi < 4; ++mi)
#pragma unroll
    for (int ni = 0; ni < 4; ++ni) {
      const int ii = wm * 64 + mi * 16 + quad * 4;
      const int jj = wn * 64 + ni * 16 + l15;
#pragma unroll
      for (int r = 0; r < 4; ++r)
        Gpb[(ii + r) * 128 + jj] = acc[mi][ni][r];
    }
}

// ---------------------------------------------------------------------------
// gram_red: G tile = sum of NS_ fp32 partials -> bf16, write both triangles.
// Mirror tile transposed through LDS (stride 137 -> ~2-way bank aliasing).
// ---------------------------------------------------------------------------
__global__ __launch_bounds__(256)
void gram_red(const float* __restrict__ Gp, short* __restrict__ G) {
  const int pair = blockIdx.x;
  int rem = pair, ti = 0;
#pragma unroll
  for (int it = 0; it < 5; ++it)
    if (rem >= 6 - ti) { rem -= 6 - ti; ++ti; }
  const int tj = ti + rem;
  const int b = blockIdx.y;
  const int i0 = ti * 128, j0 = tj * 128;
  const bool diag = (ti == tj);
  const int tid = threadIdx.x;

  __shared__ short Ts[128 * 137];    // 35072 B

  const float4* P = (const float4*)(Gp + (((size_t)b * 21 + pair) * NS_) * (128 * 128));
  short* Gb = G + (size_t)b * C_ * C_;

#pragma unroll
  for (int it = 0; it < 16; ++it) {
    const int q = tid + it * 256;          // float4 index 0..4095
    const int row = q >> 5;
    const int c4 = q & 31;
    float4 v = P[q];
    const float4 v1 = P[q + 4096];
    const float4 v2 = P[q + 8192];
    const float4 v3 = P[q + 12288];
    v.x += v1.x + v2.x + v3.x;
    v.y += v1.y + v2.y + v3.y;
    v.z += v1.z + v2.z + v3.z;
    v.w += v1.w + v2.w + v3.w;
    s16x4 sv;
    sv[0] = f2bf(v.x); sv[1] = f2bf(v.y); sv[2] = f2bf(v.z); sv[3] = f2bf(v.w);
    *(s16x4*)&Gb[(size_t)(i0 + row) * C_ + j0 + c4 * 4] = sv;
    if (!diag) {
#pragma unroll
      for (int c = 0; c < 4; ++c)
        Ts[(c4 * 4 + c) * 137 + row] = sv[c];
    }
  }
  if (!diag) {
    __syncthreads();
#pragma unroll
    for (int p = 0; p < 8; ++p) {
      const int id = tid + p * 256;        // 0..2047
      const int j = id >> 4, cs = (id & 15) * 8;
      *(s16x8*)&Gb[(size_t)(j0 + j) * C_ + i0 + cs] = *(const s16x8*)&Ts[j * 137 + cs];
    }
  }
}

// ---------------------------------------------------------------------------
// gemm_fb: Out[z][m][n] (bf16) = sum_k A[m][k] (fp32) * Bb[z][n][k] (bf16).
// NT-form MFMA GEMM (B operand given row-major over k). 128x128 tile, BK=32.
// Used for: Y = W_qk @ G   (G symmetric => G[n][k] == G[k][n])
//           Mb = w_proj @ AV (via AV^T stored row-major)
// ---------------------------------------------------------------------------
__global__ __launch_bounds__(256)
void gemm_fb(const float* __restrict__ A, const short* __restrict__ Bb,
             short* __restrict__ Out, size_t sB, size_t sO) {
  const int z = blockIdx.z;
  const int n0 = blockIdx.x * 128;
  const int m0 = blockIdx.y * 128;
  const int tid = threadIdx.x;
  const int lane = tid & 63, wave = tid >> 6;
  const int l15 = lane & 15, quad = lane >> 4;
  const int wm = wave & 1, wn = wave >> 1;

  __shared__ __align__(16) short As[128 * 40];
  __shared__ __align__(16) short Bs[128 * 40];

  const int ar = tid >> 1;
  const int ak = (tid & 1) * 16;
  const float* ap = A + (size_t)(m0 + ar) * C_ + ak;
  const short* bp = Bb + (size_t)z * sB + (size_t)(n0 + ar) * C_ + ak;

  f32x4 acc[4][4] = {};

  for (int k0 = 0; k0 < C_; k0 += 32) {
    const float4 a0 = *(const float4*)(ap + k0 + 0);
    const float4 a1 = *(const float4*)(ap + k0 + 4);
    const float4 a2 = *(const float4*)(ap + k0 + 8);
    const float4 a3 = *(const float4*)(ap + k0 + 12);
    const s16x8 b0 = *(const s16x8*)(bp + k0 + 0);
    const s16x8 b1 = *(const s16x8*)(bp + k0 + 8);
    __syncthreads();
    *(s16x8*)&As[ar * 40 + ak]     = pack8(a0, a1);
    *(s16x8*)&As[ar * 40 + ak + 8] = pack8(a2, a3);
    *(s16x8*)&Bs[ar * 40 + ak]     = b0;
    *(s16x8*)&Bs[ar * 40 + ak + 8] = b1;
    __syncthreads();
    s16x8 af[4];
#pragma unroll
    for (int mi = 0; mi < 4; ++mi)
      af[mi] = *(const s16x8*)&As[(wm * 64 + mi * 16 + l15) * 40 + quad * 8];
#pragma unroll
    for (int ni = 0; ni < 4; ++ni) {
      const s16x8 bf = *(const s16x8*)&Bs[(wn * 64 + ni * 16 + l15) * 40 + quad * 8];
#pragma unroll
      for (int mi = 0; mi < 4; ++mi)
        acc[mi][ni] = __builtin_amdgcn_mfma_f32_16x16x32_bf16(af[mi], bf, acc[mi][ni], 0, 0, 0);
    }
  }

  short* ob = Out + (size_t)z * sO;
#pragma unroll
  for (int mi = 0; mi < 4; ++mi) {
    const int m = m0 + wm * 64 + mi * 16 + quad * 4;
#pragma unroll
    for (int ni = 0; ni < 4; ++ni) {
      const int n = n0 + wn * 64 + ni * 16 + l15;
#pragma unroll
      for (int r = 0; r < 4; ++r)
        ob[(size_t)(m + r) * C_ + n] = f2bf(acc[mi][ni][r]);
    }
  }
}

// ---------------------------------------------------------------------------
// row_norms: norms for q (first 768 rows of Y) and k (next 768) per batch.
// ||q_d||^2 = dot(Y[row], w_qkv[row]) since Y = W_qk G, G = X^T X.
// One wave per row.
// ---------------------------------------------------------------------------
__global__ __launch_bounds__(256)
void row_norms(const short* __restrict__ Y, const float* __restrict__ w_qkv,
               float* __restrict__ norms) {
  const int b = blockIdx.y;
  const int m = blockIdx.x * 4 + (threadIdx.x >> 6);   // 0..1535
  const int lane = threadIdx.x & 63;
  const short* y = Y + ((size_t)b * 1536 + m) * C_;
  const float* w = w_qkv + (size_t)m * C_;
  float s = 0.f;
#pragma unroll
  for (int j = 0; j < 3; ++j) {
    const int o = j * 256 + lane * 4;
    const s16x4 yv = *(const s16x4*)(y + o);
    const float4 wv = *(const float4*)(w + o);
    s += bf2f((unsigned short)yv[0]) * wv.x + bf2f((unsigned short)yv[1]) * wv.y +
         bf2f((unsigned short)yv[2]) * wv.z + bf2f((unsigned short)yv[3]) * wv.w;
  }
#pragma unroll
  for (int o = 32; o > 0; o >>= 1) s += __shfl_xor(s, o);
  if (lane == 0) {
    int idx;
    if (m < 768) idx = (b * 8 + m / 96) * 96 + (m % 96);
    else { const int mm = m - 768; idx = B_ * H_ * 96 + (b * 8 + mm / 96) * 96 + (mm % 96); }
    norms[idx] = s;
  }
}

// ---------------------------------------------------------------------------
// s_attn: per (b,h): S_raw = Yq_h @ Wk_h^T via MFMA (K=768), scale by
// temperature / (|q_d| |k_e|), row softmax, store attn (fp32) to S.
// ---------------------------------------------------------------------------
__global__ __launch_bounds__(256)
void s_attn(const short* __restrict__ Y, const float* __restrict__ w_qkv,
            const float* __restrict__ norms, const float* __restrict__ temp,
            float* __restrict__ S) {
  const int bh = blockIdx.x;
  const int b = bh >> 3, h = bh & 7;
  const int tid = threadIdx.x;
  const int lane = tid & 63, wave = tid >> 6;
  const int l15 = lane & 15, quad = lane >> 4;

  __shared__ __align__(16) float Sf[96 * 97];   // 37248 B; aliased as bf16 staging
  __shared__ float qsc[96], ksc[96];
  short* Ys = (short*)Sf;                // 96*72 shorts
  short* Ks = (short*)Sf + 96 * 72;      // 96*72 shorts (27648 B total)

  if (tid < 96)
    qsc[tid] = temp[h] / fmaxf(sqrtf(norms[bh * 96 + tid]), EPSN);
  else if (tid < 192)
    ksc[tid - 96] = 1.0f / fmaxf(sqrtf(norms[B_ * H_ * 96 + bh * 96 + (tid - 96)]), EPSN);

  const short* yb = Y + ((size_t)b * 1536 + h * 96) * C_;
  const float* wk = w_qkv + (size_t)(C_ + h * 96) * C_;

  f32x4 sc[9] = {};
  for (int k0 = 0; k0 < C_; k0 += 64) {
    s16x8 yv[3];
    float4 wv[3][2];
#pragma unroll
    for (int j = 0; j < 3; ++j) {
      const int id = tid + j * 256;           // 0..767
      const int r = id >> 3, c8 = (id & 7) * 8;
      yv[j] = *(const s16x8*)(yb + (size_t)r * C_ + k0 + c8);
      wv[j][0] = *(const float4*)(wk + (size_t)r * C_ + k0 + c8);
      wv[j][1] = *(const float4*)(wk + (size_t)r * C_ + k0 + c8 + 4);
    }
    __syncthreads();
#pragma unroll
    for (int j = 0; j < 3; ++j) {
      const int id = tid + j * 256;
      const int r = id >> 3, c8 = (id & 7) * 8;
      *(s16x8*)&Ys[r * 72 + c8] = yv[j];
      *(s16x8*)&Ks[r * 72 + c8] = pack8(wv[j][0], wv[j][1]);
    }
    __syncthreads();
#pragma unroll
    for (int j = 0; j < 9; ++j) {
      const int t = wave * 9 + j, dt = t / 6, et = t % 6;
#pragma unroll
      for (int kk = 0; kk < 64; kk += 32) {
        const s16x8 a  = *(const s16x8*)&Ys[(dt * 16 + l15) * 72 + kk + quad * 8];
        const s16x8 bb = *(const s16x8*)&Ks[(et * 16 + l15) * 72 + kk + quad * 8];
        sc[j] = __builtin_amdgcn_mfma_f32_16x16x32_bf16(a, bb, sc[j], 0, 0, 0);
      }
    }
  }
  __syncthreads();
#pragma unroll
  for (int j = 0; j < 9; ++j) {
    const int t = wave * 9 + j, dt = t / 6, et = t % 6;
    const int e = et * 16 + l15;
    const float kf = ksc[e];
#pragma unroll
    for (int r = 0; r < 4; ++r) {
      const int d = dt * 16 + quad * 4 + r;
      Sf[d * 97 + e] = sc[j][r] * qsc[d] * kf;
    }
  }
  __syncthreads();
  float* Sb = S + (size_t)bh * (HD_ * HD_);
  for (int rr = 0; rr < 24; ++rr) {
    const int d = wave * 24 + rr;
    const float v0 = Sf[d * 97 + lane];
    const float v1 = (lane < 32) ? Sf[d * 97 + 64 + lane] : -1e30f;
    float mx = fmaxf(v0, v1);
#pragma unroll
    for (int o = 32; o > 0; o >>= 1) mx = fmaxf(mx, __shfl_xor(mx, o));
    const float e0 = __expf(v0 - mx);
    const float e1 = (lane < 32) ? __expf(v1 - mx) : 0.0f;
    float sum = e0 + e1;
#pragma unroll
    for (int o = 32; o > 0; o >>= 1) sum += __shfl_xor(sum, o);
    const float inv = 1.0f / sum;
    Sb[d * 96 + lane] = e0 * inv;
    if (lane < 32) Sb[d * 96 + 64 + lane] = e1 * inv;
  }
}

// ---------------------------------------------------------------------------
// av_gemm: AVt[b][c][h*96+d] (bf16) = sum_e attn[bh][d][e] * w_qkv[2C+h*96+e][c]
// (transposed + bf16 output so the w_proj GEMM can run as NT MFMA)
// ---------------------------------------------------------------------------
__global__ __launch_bounds__(256)
void av_gemm(const float* __restrict__ S, const float* __restrict__ w_qkv,
             short* __restrict__ AVt) {
  const int bh = blockIdx.x;
  const int b = bh >> 3, h = bh & 7;
  const int ct = blockIdx.y * 64;
  const int tid = threadIdx.x;
  __shared__ float at[96 * 97];
  __shared__ float wv[96 * 64];
  const float* Sb = S + (size_t)bh * (HD_ * HD_);
  for (int i = tid; i < 96 * 96; i += 256)
    at[(i / 96) * 97 + (i % 96)] = Sb[i];
  for (int i = tid; i < 96 * 64; i += 256) {
    const int e = i >> 6, c = i & 63;
    wv[e * 64 + c] = w_qkv[(size_t)(2 * C_ + h * 96 + e) * C_ + ct + c];
  }
  __syncthreads();
  const int d0 = (tid >> 4) * 6;
  const int c0 = (tid & 15) * 4;
  float acc[6][4] = {};
  for (int e = 0; e < 96; ++e) {
    const float4 bv = *(const float4*)&wv[e * 64 + c0];
    float aa[6];
#pragma unroll
    for (int i = 0; i < 6; ++i) aa[i] = at[(d0 + i) * 97 + e];
#pragma unroll
    for (int i = 0; i < 6; ++i) {
      acc[i][0] += aa[i] * bv.x; acc[i][1] += aa[i] * bv.y;
      acc[i][2] += aa[i] * bv.z; acc[i][3] += aa[i] * bv.w;
    }
  }
  short* AVb = AVt + (size_t)b * C_ * C_;
#pragma unroll
  for (int i = 0; i < 6; ++i)
#pragma unroll
    for (int j = 0; j < 4; ++j)
      AVb[(size_t)(ct + c0 + j) * C_ + h * 96 + d0 + i] = f2bf(acc[i][j]);
}

// ---------------------------------------------------------------------------
// Final GEMM via bf16 MFMA: out[z][m][n] = sum_k x[z][m][k]*Mb[z][n][k] + bias[n]
// ---------------------------------------------------------------------------
__global__ __launch_bounds__(256)
void gemm_xm(const float* __restrict__ x, const short* __restrict__ Mb,
             const float* __restrict__ bias, float* __restrict__ out) {
  const int z = blockIdx.z;
  const int n0 = blockIdx.x * 128;
  const int m0 = blockIdx.y * 128;
  const int tid = threadIdx.x;
  const int lane = tid & 63;
  const int wave = tid >> 6;
  const int l15 = lane & 15;
  const int quad = lane >> 4;
  const int wm = wave & 1;
  const int wn = wave >> 1;

  __shared__ __align__(16) short As[128 * 40];
  __shared__ __align__(16) short Bs[128 * 40];

  const int ar = tid >> 1;
  const int ak = (tid & 1) * 16;
  const float* xp = x + ((size_t)z * N_ + m0 + ar) * C_ + ak;
  const short* mp = Mb + (size_t)z * C_ * C_ + (size_t)(n0 + ar) * C_ + ak;

  f32x4 acc[4][4] = {};

  for (int k0 = 0; k0 < C_; k0 += 32) {
    const float4 a0 = *(const float4*)(xp + k0 + 0);
    const float4 a1 = *(const float4*)(xp + k0 + 4);
    const float4 a2 = *(const float4*)(xp + k0 + 8);
    const float4 a3 = *(const float4*)(xp + k0 + 12);
    const s16x8 b0 = *(const s16x8*)(mp + k0 + 0);
    const s16x8 b1 = *(const s16x8*)(mp + k0 + 8);
    __syncthreads();
    *(s16x8*)&As[ar * 40 + ak]     = pack8(a0, a1);
    *(s16x8*)&As[ar * 40 + ak + 8] = pack8(a2, a3);
    *(s16x8*)&Bs[ar * 40 + ak]     = b0;
    *(s16x8*)&Bs[ar * 40 + ak + 8] = b1;
    __syncthreads();
    s16x8 af[4];
#pragma unroll
    for (int mi = 0; mi < 4; ++mi)
      af[mi] = *(const s16x8*)&As[(wm * 64 + mi * 16 + l15) * 40 + quad * 8];
#pragma unroll
    for (int ni = 0; ni < 4; ++ni) {
      const s16x8 bf = *(const s16x8*)&Bs[(wn * 64 + ni * 16 + l15) * 40 + quad * 8];
#pragma unroll
      for (int mi = 0; mi < 4; ++mi)
        acc[mi][ni] = __builtin_amdgcn_mfma_f32_16x16x32_bf16(af[mi], bf, acc[mi][ni], 0, 0, 0);
    }
  }

  float bv[4];
#pragma unroll
  for (int ni = 0; ni < 4; ++ni) bv[ni] = bias[n0 + wn * 64 + ni * 16 + l15];
#pragma unroll
  for (int mi = 0; mi < 4; ++mi) {
    const int m = m0 + wm * 64 + mi * 16 + quad * 4;
#pragma unroll
    for (int ni = 0; ni < 4; ++ni) {
      const int n = n0 + wn * 64 + ni * 16 + l15;
      float* dst = out + ((size_t)z * N_ + m) * C_ + n;
#pragma unroll
      for (int r = 0; r < 4; ++r)
        dst[(size_t)r * C_] = acc[mi][ni][r] + bv[ni];
    }
  }
}

// ---------------------------------------------------------------------------
extern "C" void kernel_launch(void* const* d_in, const int* in_sizes, int n_in,
                              void* d_out, int out_size, void* d_ws, size_t ws_size,
                              hipStream_t stream) {
  const float* x      = (const float*)d_in[0];
  const float* w_qkv  = (const float*)d_in[1];
  const float* temp   = (const float*)d_in[2];
  const float* w_proj = (const float*)d_in[3];
  const float* b_proj = (const float*)d_in[4];
  float* out = (float*)d_out;

  // workspace layout (peak ~56 MiB, with liveness overlap):
  //   S     : 589824 f        [s_attn .. av_gemm]
  //   norms : 12288 f
  //   G     : 4718592 bf16    [gram_red .. gemm_fb(Y)]   (later reused as AVt)
  //   Mb    : 4718592 bf16    [gemm_fb(Mb) .. gemm_xm]
  //   Y     : 9437184 bf16    [gemm_fb(Y) .. s_attn]
  //   Gp    : 21*16384*NS_*B_ f (44 MiB) OVERLAPS Mb+Y (+beyond); dead after
  //           gram_red, before Mb/Y are written.
  float* ws    = (float*)d_ws;
  float* S     = ws;
  float* norms = S + (size_t)B_ * H_ * HD_ * HD_;
  short* G     = (short*)(norms + 2 * B_ * H_ * HD_);
  short* AVt   = G;                                  // alias, G dead by then
  short* Mb    = G + (size_t)B_ * C_ * C_;
  short* Y     = Mb + (size_t)B_ * C_ * C_;
  float* Gp    = (float*)Mb;                         // 44 MiB, dead early

  // Partial Gram: Gp[(b,pair,split)] = chunk contribution (fp32)
  gram_p<<<dim3(21, NS_, B_), 256, 0, stream>>>(x, Gp);

  // Reduce partials -> G (bf16, both triangles)
  gram_red<<<dim3(21, B_), 256, 0, stream>>>(Gp, G);

  // Y_b = W_qk @ G_b   (G symmetric -> NT form)
  gemm_fb<<<dim3(C_ / 128, 1536 / 128, B_), 256, 0, stream>>>(
      w_qkv, G, Y, (size_t)C_ * C_, (size_t)1536 * C_);

  // per-row norms: ||q_d||^2 = dot(Y row, W row)
  row_norms<<<dim3(1536 / 4, B_), 256, 0, stream>>>(Y, w_qkv, norms);

  // S = softmax( temp * Yq Wk^T / (|q||k|) )  per (b,h)
  s_attn<<<B_ * H_, 256, 0, stream>>>(Y, w_qkv, norms, temp, S);

  // AVt_b[c][vchan] = (attn @ W_v)^T  (bf16)
  av_gemm<<<dim3(B_ * H_, C_ / 64), 256, 0, stream>>>(S, w_qkv, AVt);

  // Mb_z = bf16( w_proj @ AV_z )  stored [cout][cin]  (NT MFMA via AVt)
  gemm_fb<<<dim3(C_ / 128, C_ / 128, B_), 256, 0, stream>>>(
      w_proj, AVt, Mb, (size_t)C_ * C_, (size_t)C_ * C_);

  // out[z] = x[z] @ Mb_z^T + bias  (bf16 MFMA)
  gemm_xm<<<dim3(C_ / 128, N_ / 128, B_), 256, 0, stream>>>(x, Mb, b_proj, out);
}

// Round 3
// 430.859 us; speedup vs baseline: 1.5944x; 1.1393x over previous
//
#include <hip/hip_runtime.h>
#include <cstdint>
#include <cstddef>

#define B_ 8
#define N_ 4096
#define C_ 768
#define H_ 8
#define HD_ 96
#define EPSN 1e-12f
#define NS_ 4          // gram split-K factor over tokens

typedef short s16x8 __attribute__((ext_vector_type(8)));   // 8 bf16 (4 VGPRs)
typedef short s16x4 __attribute__((ext_vector_type(4)));
typedef float f32x4 __attribute__((ext_vector_type(4)));   // MFMA acc

// fp32 -> bf16 (RNE) as raw short bits
static __device__ __forceinline__ short f2bf(float f) {
  unsigned u = __float_as_uint(f);
  unsigned r = (u + 0x7fff + ((u >> 16) & 1)) >> 16;
  return (short)r;
}
static __device__ __forceinline__ float bf2f(unsigned short s) {
  return __uint_as_float(((unsigned)s) << 16);
}
static __device__ __forceinline__ s16x8 pack8(const float4 a, const float4 b) {
  s16x8 r;
  r[0] = f2bf(a.x); r[1] = f2bf(a.y); r[2] = f2bf(a.z); r[3] = f2bf(a.w);
  r[4] = f2bf(b.x); r[5] = f2bf(b.y); r[6] = f2bf(b.z); r[7] = f2bf(b.w);
  return r;
}

// token-index swizzle for transposed LDS staging: XOR the 8-token block index
// with low bits of (ch>>2) so the 4-token s16x4 writes spread across banks.
#define TSW(ch, t) ((t) ^ ((((ch) >> 2) & 7) << 3))

// ---------------------------------------------------------------------------
// gram_p: partial Gram. For pair tile (ti,tj) and token chunk s:
//   Gp[((b*21+pair)*NS+s)] (128x128 fp32) = sum_{n in chunk} X[n,i0+:]^T X[n,j0+:]
// 1D grid 672 = 8 XCD x 84, XCD-swizzled: all 21 pairs of one (b,split) chunk
// run consecutively on one XCD -> the 3 MB x-chunk stays L2-resident.
// ---------------------------------------------------------------------------
__global__ __launch_bounds__(256)
void gram_p(const float* __restrict__ x, float* __restrict__ Gp) {
  const int f = blockIdx.x;
  const int xcd = f & 7;
  const int t = f >> 3;            // 0..83
  const int pair = t % 21;
  const int cdiv = t / 21;         // 0..3
  const int c = xcd + 8 * cdiv;    // 0..31
  const int split = c & 3;
  const int b = c >> 2;

  int rem = pair, ti = 0;
#pragma unroll
  for (int it = 0; it < 5; ++it)
    if (rem >= 6 - ti) { rem -= 6 - ti; ++ti; }
  const int tj = ti + rem;
  const int i0 = ti * 128, j0 = tj * 128;
  const bool diag = (ti == tj);

  const int tid = threadIdx.x;
  const int lane = tid & 63, wave = tid >> 6;
  const int l15 = lane & 15, quad = lane >> 4;
  const int wm = wave & 1, wn = wave >> 1;

  __shared__ __align__(16) short smem[2 * 128 * 72];   // 36864 B
  short* At = smem;
  short* Bt = smem + 128 * 72;

  const int tg = tid >> 4;       // 0..15 -> t0 = 4*tg
  const int cg = tid & 15;       // 0..15 -> c0 = 4*cg (and +64)
  const int t0 = tg * 4;
  const int c0 = cg * 4;
  const float* xb = x + (size_t)b * N_ * C_;

  f32x4 acc[4][4] = {};

  const int nbeg = split * (N_ / NS_);
  const int nend = nbeg + (N_ / NS_);
  for (int n0 = nbeg; n0 < nend; n0 += 64) {
    float4 la[2][4], lb[2][4];
#pragma unroll
    for (int q = 0; q < 2; ++q)
#pragma unroll
      for (int r = 0; r < 4; ++r)
        la[q][r] = *(const float4*)(xb + (size_t)(n0 + t0 + r) * C_ + i0 + c0 + q * 64);
    if (!diag) {
#pragma unroll
      for (int q = 0; q < 2; ++q)
#pragma unroll
        for (int r = 0; r < 4; ++r)
          lb[q][r] = *(const float4*)(xb + (size_t)(n0 + t0 + r) * C_ + j0 + c0 + q * 64);
    }
    __syncthreads();
#pragma unroll
    for (int q = 0; q < 2; ++q)
#pragma unroll
      for (int cc = 0; cc < 4; ++cc) {
        const int ch = c0 + q * 64 + cc;
        s16x4 v;
        v[0] = f2bf(((const float*)&la[q][0])[cc]);
        v[1] = f2bf(((const float*)&la[q][1])[cc]);
        v[2] = f2bf(((const float*)&la[q][2])[cc]);
        v[3] = f2bf(((const float*)&la[q][3])[cc]);
        *(s16x4*)&At[ch * 72 + TSW(ch, t0)] = v;
      }
    if (!diag) {
#pragma unroll
      for (int q = 0; q < 2; ++q)
#pragma unroll
        for (int cc = 0; cc < 4; ++cc) {
          const int ch = c0 + q * 64 + cc;
          s16x4 v;
          v[0] = f2bf(((const float*)&lb[q][0])[cc]);
          v[1] = f2bf(((const float*)&lb[q][1])[cc]);
          v[2] = f2bf(((const float*)&lb[q][2])[cc]);
          v[3] = f2bf(((const float*)&lb[q][3])[cc]);
          *(s16x4*)&Bt[ch * 72 + TSW(ch, t0)] = v;
        }
    }
    __syncthreads();
    const short* Bre = diag ? At : Bt;
#pragma unroll
    for (int ks = 0; ks < 64; ks += 32) {
      s16x8 af[4], bfr[4];
#pragma unroll
      for (int mi = 0; mi < 4; ++mi) {
        const int ch = wm * 64 + mi * 16 + l15;
        af[mi] = *(const s16x8*)&At[ch * 72 + TSW(ch, ks + quad * 8)];
      }
#pragma unroll
      for (int ni = 0; ni < 4; ++ni) {
        const int ch = wn * 64 + ni * 16 + l15;
        bfr[ni] = *(const s16x8*)&Bre[ch * 72 + TSW(ch, ks + quad * 8)];
      }
#pragma unroll
      for (int ni = 0; ni < 4; ++ni)
#pragma unroll
        for (int mi = 0; mi < 4; ++mi)
          acc[mi][ni] = __builtin_amdgcn_mfma_f32_16x16x32_bf16(af[mi], bfr[ni], acc[mi][ni], 0, 0, 0);
    }
  }

  float* Gpb = Gp + (((size_t)b * 21 + pair) * NS_ + split) * (128 * 128);
#pragma unroll
  for (int mi = 0; mi < 4; ++mi)
#pragma unroll
    for (int ni = 0; ni < 4; ++ni) {
      const int ii = wm * 64 + mi * 16 + quad * 4;
      const int jj = wn * 64 + ni * 16 + l15;
#pragma unroll
      for (int r = 0; r < 4; ++r)
        Gpb[(ii + r) * 128 + jj] = acc[mi][ni][r];
    }
}

// ---------------------------------------------------------------------------
// gram_red: G tile = sum of NS_ fp32 partials -> bf16, write both triangles.
// Mirror tile transposed through LDS (stride 137 -> ~2-way bank aliasing).
// ---------------------------------------------------------------------------
__global__ __launch_bounds__(256)
void gram_red(const float* __restrict__ Gp, short* __restrict__ G) {
  const int pair = blockIdx.x;
  int rem = pair, ti = 0;
#pragma unroll
  for (int it = 0; it < 5; ++it)
    if (rem >= 6 - ti) { rem -= 6 - ti; ++ti; }
  const int tj = ti + rem;
  const int b = blockIdx.y;
  const int i0 = ti * 128, j0 = tj * 128;
  const bool diag = (ti == tj);
  const int tid = threadIdx.x;

  __shared__ short Ts[128 * 137];    // 35072 B

  const float4* P = (const float4*)(Gp + (((size_t)b * 21 + pair) * NS_) * (128 * 128));
  short* Gb = G + (size_t)b * C_ * C_;

#pragma unroll
  for (int it = 0; it < 16; ++it) {
    const int q = tid + it * 256;          // float4 index 0..4095
    const int row = q >> 5;
    const int c4 = q & 31;
    float4 v = P[q];
    const float4 v1 = P[q + 4096];
    const float4 v2 = P[q + 8192];
    const float4 v3 = P[q + 12288];
    v.x += v1.x + v2.x + v3.x;
    v.y += v1.y + v2.y + v3.y;
    v.z += v1.z + v2.z + v3.z;
    v.w += v1.w + v2.w + v3.w;
    s16x4 sv;
    sv[0] = f2bf(v.x); sv[1] = f2bf(v.y); sv[2] = f2bf(v.z); sv[3] = f2bf(v.w);
    *(s16x4*)&Gb[(size_t)(i0 + row) * C_ + j0 + c4 * 4] = sv;
    if (!diag) {
#pragma unroll
      for (int c = 0; c < 4; ++c)
        Ts[(c4 * 4 + c) * 137 + row] = sv[c];
    }
  }
  if (!diag) {
    __syncthreads();
#pragma unroll
    for (int p = 0; p < 8; ++p) {
      const int id = tid + p * 256;        // 0..2047
      const int j = id >> 4, cs = (id & 15) * 8;
      *(s16x8*)&Gb[(size_t)(j0 + j) * C_ + i0 + cs] = *(const s16x8*)&Ts[j * 137 + cs];
    }
  }
}

// ---------------------------------------------------------------------------
// gemm_fb: Out[z][m][n] (bf16) = sum_k A[m][k] (fp32) * Bb[z][n][k] (bf16).
// NT-form MFMA GEMM (B operand given row-major over k). 128x128 tile, BK=32.
// Used for: Y = W_qk @ G   (G symmetric => G[n][k] == G[k][n])
//           Mb = w_proj @ AV (via AV^T stored row-major)
// ---------------------------------------------------------------------------
__global__ __launch_bounds__(256)
void gemm_fb(const float* __restrict__ A, const short* __restrict__ Bb,
             short* __restrict__ Out, size_t sB, size_t sO) {
  const int z = blockIdx.z;
  const int n0 = blockIdx.x * 128;
  const int m0 = blockIdx.y * 128;
  const int tid = threadIdx.x;
  const int lane = tid & 63, wave = tid >> 6;
  const int l15 = lane & 15, quad = lane >> 4;
  const int wm = wave & 1, wn = wave >> 1;

  __shared__ __align__(16) short As[128 * 40];
  __shared__ __align__(16) short Bs[128 * 40];

  const int ar = tid >> 1;
  const int ak = (tid & 1) * 16;
  const float* ap = A + (size_t)(m0 + ar) * C_ + ak;
  const short* bp = Bb + (size_t)z * sB + (size_t)(n0 + ar) * C_ + ak;

  f32x4 acc[4][4] = {};

  for (int k0 = 0; k0 < C_; k0 += 32) {
    const float4 a0 = *(const float4*)(ap + k0 + 0);
    const float4 a1 = *(const float4*)(ap + k0 + 4);
    const float4 a2 = *(const float4*)(ap + k0 + 8);
    const float4 a3 = *(const float4*)(ap + k0 + 12);
    const s16x8 b0 = *(const s16x8*)(bp + k0 + 0);
    const s16x8 b1 = *(const s16x8*)(bp + k0 + 8);
    __syncthreads();
    *(s16x8*)&As[ar * 40 + ak]     = pack8(a0, a1);
    *(s16x8*)&As[ar * 40 + ak + 8] = pack8(a2, a3);
    *(s16x8*)&Bs[ar * 40 + ak]     = b0;
    *(s16x8*)&Bs[ar * 40 + ak + 8] = b1;
    __syncthreads();
    s16x8 af[4];
#pragma unroll
    for (int mi = 0; mi < 4; ++mi)
      af[mi] = *(const s16x8*)&As[(wm * 64 + mi * 16 + l15) * 40 + quad * 8];
#pragma unroll
    for (int ni = 0; ni < 4; ++ni) {
      const s16x8 bf = *(const s16x8*)&Bs[(wn * 64 + ni * 16 + l15) * 40 + quad * 8];
#pragma unroll
      for (int mi = 0; mi < 4; ++mi)
        acc[mi][ni] = __builtin_amdgcn_mfma_f32_16x16x32_bf16(af[mi], bf, acc[mi][ni], 0, 0, 0);
    }
  }

  short* ob = Out + (size_t)z * sO;
#pragma unroll
  for (int mi = 0; mi < 4; ++mi) {
    const int m = m0 + wm * 64 + mi * 16 + quad * 4;
#pragma unroll
    for (int ni = 0; ni < 4; ++ni) {
      const int n = n0 + wn * 64 + ni * 16 + l15;
#pragma unroll
      for (int r = 0; r < 4; ++r)
        ob[(size_t)(m + r) * C_ + n] = f2bf(acc[mi][ni][r]);
    }
  }
}

// ---------------------------------------------------------------------------
// row_norms: norms for q (first 768 rows of Y) and k (next 768) per batch.
// ||q_d||^2 = dot(Y[row], w_qkv[row]) since Y = W_qk G, G = X^T X.
// One wave per row.
// ---------------------------------------------------------------------------
__global__ __launch_bounds__(256)
void row_norms(const short* __restrict__ Y, const float* __restrict__ w_qkv,
               float* __restrict__ norms) {
  const int b = blockIdx.y;
  const int m = blockIdx.x * 4 + (threadIdx.x >> 6);   // 0..1535
  const int lane = threadIdx.x & 63;
  const short* y = Y + ((size_t)b * 1536 + m) * C_;
  const float* w = w_qkv + (size_t)m * C_;
  float s = 0.f;
#pragma unroll
  for (int j = 0; j < 3; ++j) {
    const int o = j * 256 + lane * 4;
    const s16x4 yv = *(const s16x4*)(y + o);
    const float4 wv = *(const float4*)(w + o);
    s += bf2f((unsigned short)yv[0]) * wv.x + bf2f((unsigned short)yv[1]) * wv.y +
         bf2f((unsigned short)yv[2]) * wv.z + bf2f((unsigned short)yv[3]) * wv.w;
  }
#pragma unroll
  for (int o = 32; o > 0; o >>= 1) s += __shfl_xor(s, o);
  if (lane == 0) {
    int idx;
    if (m < 768) idx = (b * 8 + m / 96) * 96 + (m % 96);
    else { const int mm = m - 768; idx = B_ * H_ * 96 + (b * 8 + mm / 96) * 96 + (mm % 96); }
    norms[idx] = s;
  }
}

// ---------------------------------------------------------------------------
// s_attn: per (b,h): S_raw = Yq_h @ Wk_h^T via MFMA (K=768), scale by
// temperature / (|q_d| |k_e|), row softmax, store attn (fp32) to S.
// ---------------------------------------------------------------------------
__global__ __launch_bounds__(256)
void s_attn(const short* __restrict__ Y, const float* __restrict__ w_qkv,
            const float* __restrict__ norms, const float* __restrict__ temp,
            float* __restrict__ S) {
  const int bh = blockIdx.x;
  const int b = bh >> 3, h = bh & 7;
  const int tid = threadIdx.x;
  const int lane = tid & 63, wave = tid >> 6;
  const int l15 = lane & 15, quad = lane >> 4;

  __shared__ __align__(16) float Sf[96 * 97];   // 37248 B; aliased as bf16 staging
  __shared__ float qsc[96], ksc[96];
  short* Ys = (short*)Sf;                // 96*72 shorts
  short* Ks = (short*)Sf + 96 * 72;      // 96*72 shorts (27648 B total)

  if (tid < 96)
    qsc[tid] = temp[h] / fmaxf(sqrtf(norms[bh * 96 + tid]), EPSN);
  else if (tid < 192)
    ksc[tid - 96] = 1.0f / fmaxf(sqrtf(norms[B_ * H_ * 96 + bh * 96 + (tid - 96)]), EPSN);

  const short* yb = Y + ((size_t)b * 1536 + h * 96) * C_;
  const float* wk = w_qkv + (size_t)(C_ + h * 96) * C_;

  f32x4 sc[9] = {};
  for (int k0 = 0; k0 < C_; k0 += 64) {
    s16x8 yv[3];
    float4 wv[3][2];
#pragma unroll
    for (int j = 0; j < 3; ++j) {
      const int id = tid + j * 256;           // 0..767
      const int r = id >> 3, c8 = (id & 7) * 8;
      yv[j] = *(const s16x8*)(yb + (size_t)r * C_ + k0 + c8);
      wv[j][0] = *(const float4*)(wk + (size_t)r * C_ + k0 + c8);
      wv[j][1] = *(const float4*)(wk + (size_t)r * C_ + k0 + c8 + 4);
    }
    __syncthreads();
#pragma unroll
    for (int j = 0; j < 3; ++j) {
      const int id = tid + j * 256;
      const int r = id >> 3, c8 = (id & 7) * 8;
      *(s16x8*)&Ys[r * 72 + c8] = yv[j];
      *(s16x8*)&Ks[r * 72 + c8] = pack8(wv[j][0], wv[j][1]);
    }
    __syncthreads();
#pragma unroll
    for (int j = 0; j < 9; ++j) {
      const int t = wave * 9 + j, dt = t / 6, et = t % 6;
#pragma unroll
      for (int kk = 0; kk < 64; kk += 32) {
        const s16x8 a  = *(const s16x8*)&Ys[(dt * 16 + l15) * 72 + kk + quad * 8];
        const s16x8 bb = *(const s16x8*)&Ks[(et * 16 + l15) * 72 + kk + quad * 8];
        sc[j] = __builtin_amdgcn_mfma_f32_16x16x32_bf16(a, bb, sc[j], 0, 0, 0);
      }
    }
  }
  __syncthreads();
#pragma unroll
  for (int j = 0; j < 9; ++j) {
    const int t = wave * 9 + j, dt = t / 6, et = t % 6;
    const int e = et * 16 + l15;
    const float kf = ksc[e];
#pragma unroll
    for (int r = 0; r < 4; ++r) {
      const int d = dt * 16 + quad * 4 + r;
      Sf[d * 97 + e] = sc[j][r] * qsc[d] * kf;
    }
  }
  __syncthreads();
  float* Sb = S + (size_t)bh * (HD_ * HD_);
  for (int rr = 0; rr < 24; ++rr) {
    const int d = wave * 24 + rr;
    const float v0 = Sf[d * 97 + lane];
    const float v1 = (lane < 32) ? Sf[d * 97 + 64 + lane] : -1e30f;
    float mx = fmaxf(v0, v1);
#pragma unroll
    for (int o = 32; o > 0; o >>= 1) mx = fmaxf(mx, __shfl_xor(mx, o));
    const float e0 = __expf(v0 - mx);
    const float e1 = (lane < 32) ? __expf(v1 - mx) : 0.0f;
    float sum = e0 + e1;
#pragma unroll
    for (int o = 32; o > 0; o >>= 1) sum += __shfl_xor(sum, o);
    const float inv = 1.0f / sum;
    Sb[d * 96 + lane] = e0 * inv;
    if (lane < 32) Sb[d * 96 + 64 + lane] = e1 * inv;
  }
}

// ---------------------------------------------------------------------------
// av_gemm: AVt[b][c][h*96+d] (bf16) = sum_e attn[bh][d][e] * w_qkv[2C+h*96+e][c]
// (transposed + bf16 output so the w_proj GEMM can run as NT MFMA)
// ---------------------------------------------------------------------------
__global__ __launch_bounds__(256)
void av_gemm(const float* __restrict__ S, const float* __restrict__ w_qkv,
             short* __restrict__ AVt) {
  const int bh = blockIdx.x;
  const int b = bh >> 3, h = bh & 7;
  const int ct = blockIdx.y * 64;
  const int tid = threadIdx.x;
  __shared__ float at[96 * 97];
  __shared__ float wv[96 * 64];
  const float* Sb = S + (size_t)bh * (HD_ * HD_);
  for (int i = tid; i < 96 * 96; i += 256)
    at[(i / 96) * 97 + (i % 96)] = Sb[i];
  for (int i = tid; i < 96 * 64; i += 256) {
    const int e = i >> 6, c = i & 63;
    wv[e * 64 + c] = w_qkv[(size_t)(2 * C_ + h * 96 + e) * C_ + ct + c];
  }
  __syncthreads();
  const int d0 = (tid >> 4) * 6;
  const int c0 = (tid & 15) * 4;
  float acc[6][4] = {};
  for (int e = 0; e < 96; ++e) {
    const float4 bv = *(const float4*)&wv[e * 64 + c0];
    float aa[6];
#pragma unroll
    for (int i = 0; i < 6; ++i) aa[i] = at[(d0 + i) * 97 + e];
#pragma unroll
    for (int i = 0; i < 6; ++i) {
      acc[i][0] += aa[i] * bv.x; acc[i][1] += aa[i] * bv.y;
      acc[i][2] += aa[i] * bv.z; acc[i][3] += aa[i] * bv.w;
    }
  }
  short* AVb = AVt + (size_t)b * C_ * C_;
#pragma unroll
  for (int i = 0; i < 6; ++i)
#pragma unroll
    for (int j = 0; j < 4; ++j)
      AVb[(size_t)(ct + c0 + j) * C_ + h * 96 + d0 + i] = f2bf(acc[i][j]);
}

// ---------------------------------------------------------------------------
// Final GEMM via bf16 MFMA: out[z][m][n] = sum_k x[z][m][k]*Mb[z][n][k] + bias[n]
// 1D grid 1536 = 8 XCD x 192, XCD-swizzled: the 6 n-blocks sharing one
// 128-row x-slice run consecutively on one XCD -> x-slice stays L2-resident.
// ---------------------------------------------------------------------------
__global__ __launch_bounds__(256)
void gemm_xm(const float* __restrict__ x, const short* __restrict__ Mb,
             const float* __restrict__ bias, float* __restrict__ out) {
  const int f = blockIdx.x;
  const int xcd = f & 7;
  const int t = f >> 3;           // 0..191
  const int j6 = t % 6;           // n-block (fast within XCD)
  const int sdiv = t / 6;         // 0..31
  const int s = xcd + 8 * sdiv;   // 0..255 (m-slice id)
  const int z = s >> 5;
  const int n0 = j6 * 128;
  const int m0 = (s & 31) * 128;
  const int tid = threadIdx.x;
  const int lane = tid & 63;
  const int wave = tid >> 6;
  const int l15 = lane & 15;
  const int quad = lane >> 4;
  const int wm = wave & 1;
  const int wn = wave >> 1;

  __shared__ __align__(16) short As[128 * 40];
  __shared__ __align__(16) short Bs[128 * 40];

  const int ar = tid >> 1;
  const int ak = (tid & 1) * 16;
  const float* xp = x + ((size_t)z * N_ + m0 + ar) * C_ + ak;
  const short* mp = Mb + (size_t)z * C_ * C_ + (size_t)(n0 + ar) * C_ + ak;

  f32x4 acc[4][4] = {};

  for (int k0 = 0; k0 < C_; k0 += 32) {
    const float4 a0 = *(const float4*)(xp + k0 + 0);
    const float4 a1 = *(const float4*)(xp + k0 + 4);
    const float4 a2 = *(const float4*)(xp + k0 + 8);
    const float4 a3 = *(const float4*)(xp + k0 + 12);
    const s16x8 b0 = *(const s16x8*)(mp + k0 + 0);
    const s16x8 b1 = *(const s16x8*)(mp + k0 + 8);
    __syncthreads();
    *(s16x8*)&As[ar * 40 + ak]     = pack8(a0, a1);
    *(s16x8*)&As[ar * 40 + ak + 8] = pack8(a2, a3);
    *(s16x8*)&Bs[ar * 40 + ak]     = b0;
    *(s16x8*)&Bs[ar * 40 + ak + 8] = b1;
    __syncthreads();
    s16x8 af[4];
#pragma unroll
    for (int mi = 0; mi < 4; ++mi)
      af[mi] = *(const s16x8*)&As[(wm * 64 + mi * 16 + l15) * 40 + quad * 8];
#pragma unroll
    for (int ni = 0; ni < 4; ++ni) {
      const s16x8 bf = *(const s16x8*)&Bs[(wn * 64 + ni * 16 + l15) * 40 + quad * 8];
#pragma unroll
      for (int mi = 0; mi < 4; ++mi)
        acc[mi][ni] = __builtin_amdgcn_mfma_f32_16x16x32_bf16(af[mi], bf, acc[mi][ni], 0, 0, 0);
    }
  }

  float bv[4];
#pragma unroll
  for (int ni = 0; ni < 4; ++ni) bv[ni] = bias[n0 + wn * 64 + ni * 16 + l15];
#pragma unroll
  for (int mi = 0; mi < 4; ++mi) {
    const int m = m0 + wm * 64 + mi * 16 + quad * 4;
#pragma unroll
    for (int ni = 0; ni < 4; ++ni) {
      const int n = n0 + wn * 64 + ni * 16 + l15;
      float* dst = out + ((size_t)z * N_ + m) * C_ + n;
#pragma unroll
      for (int r = 0; r < 4; ++r)
        dst[(size_t)r * C_] = acc[mi][ni][r] + bv[ni];
    }
  }
}

// ---------------------------------------------------------------------------
extern "C" void kernel_launch(void* const* d_in, const int* in_sizes, int n_in,
                              void* d_out, int out_size, void* d_ws, size_t ws_size,
                              hipStream_t stream) {
  const float* x      = (const float*)d_in[0];
  const float* w_qkv  = (const float*)d_in[1];
  const float* temp   = (const float*)d_in[2];
  const float* w_proj = (const float*)d_in[3];
  const float* b_proj = (const float*)d_in[4];
  float* out = (float*)d_out;

  // workspace layout (peak ~56 MiB, with liveness overlap):
  //   S     : 589824 f        [s_attn .. av_gemm]
  //   norms : 12288 f
  //   G     : 4718592 bf16    [gram_red .. gemm_fb(Y)]   (later reused as AVt)
  //   Mb    : 4718592 bf16    [gemm_fb(Mb) .. gemm_xm]
  //   Y     : 9437184 bf16    [gemm_fb(Y) .. s_attn]
  //   Gp    : 21*16384*NS_*B_ f (44 MiB) OVERLAPS Mb+Y (+beyond); dead after
  //           gram_red, before Mb/Y are written.
  float* ws    = (float*)d_ws;
  float* S     = ws;
  float* norms = S + (size_t)B_ * H_ * HD_ * HD_;
  short* G     = (short*)(norms + 2 * B_ * H_ * HD_);
  short* AVt   = G;                                  // alias, G dead by then
  short* Mb    = G + (size_t)B_ * C_ * C_;
  short* Y     = Mb + (size_t)B_ * C_ * C_;
  float* Gp    = (float*)Mb;                         // 44 MiB, dead early

  // Partial Gram: Gp[(b,pair,split)] = chunk contribution (fp32)
  gram_p<<<21 * NS_ * B_, 256, 0, stream>>>(x, Gp);

  // Reduce partials -> G (bf16, both triangles)
  gram_red<<<dim3(21, B_), 256, 0, stream>>>(Gp, G);

  // Y_b = W_qk @ G_b   (G symmetric -> NT form)
  gemm_fb<<<dim3(C_ / 128, 1536 / 128, B_), 256, 0, stream>>>(
      w_qkv, G, Y, (size_t)C_ * C_, (size_t)1536 * C_);

  // per-row norms: ||q_d||^2 = dot(Y row, W row)
  row_norms<<<dim3(1536 / 4, B_), 256, 0, stream>>>(Y, w_qkv, norms);

  // S = softmax( temp * Yq Wk^T / (|q||k|) )  per (b,h)
  s_attn<<<B_ * H_, 256, 0, stream>>>(Y, w_qkv, norms, temp, S);

  // AVt_b[c][vchan] = (attn @ W_v)^T  (bf16)
  av_gemm<<<dim3(B_ * H_, C_ / 64), 256, 0, stream>>>(S, w_qkv, AVt);

  // Mb_z = bf16( w_proj @ AV_z )  stored [cout][cin]  (NT MFMA via AVt)
  gemm_fb<<<dim3(C_ / 128, C_ / 128, B_), 256, 0, stream>>>(
      w_proj, AVt, Mb, (size_t)C_ * C_, (size_t)C_ * C_);

  // out[z] = x[z] @ Mb_z^T + bias  (bf16 MFMA)
  gemm_xm<<<C_ / 128 * (N_ / 128) * B_, 256, 0, stream>>>(x, Mb, b_proj, out);
}

// Round 4
// 430.614 us; speedup vs baseline: 1.5953x; 1.0006x over previous
//
#include <hip/hip_runtime.h>
#include <cstdint>
#include <cstddef>

#define B_ 8
#define N_ 4096
#define C_ 768
#define H_ 8
#define HD_ 96
#define EPSN 1e-12f
#define NS_ 4          // gram split-K factor over tokens

typedef short s16x8 __attribute__((ext_vector_type(8)));   // 8 bf16 (4 VGPRs)
typedef short s16x4 __attribute__((ext_vector_type(4)));
typedef float f32x4 __attribute__((ext_vector_type(4)));   // MFMA acc

// fp32 -> bf16 (RNE) as raw short bits
static __device__ __forceinline__ short f2bf(float f) {
  unsigned u = __float_as_uint(f);
  unsigned r = (u + 0x7fff + ((u >> 16) & 1)) >> 16;
  return (short)r;
}
static __device__ __forceinline__ float bf2f(unsigned short s) {
  return __uint_as_float(((unsigned)s) << 16);
}
static __device__ __forceinline__ s16x8 pack8(const float4 a, const float4 b) {
  s16x8 r;
  r[0] = f2bf(a.x); r[1] = f2bf(a.y); r[2] = f2bf(a.z); r[3] = f2bf(a.w);
  r[4] = f2bf(b.x); r[5] = f2bf(b.y); r[6] = f2bf(b.z); r[7] = f2bf(b.w);
  return r;
}

// token-index swizzle for transposed LDS staging (gram): XOR the token index
// with low bits of (ch>>2) so the 4-token s16x4 writes spread across banks.
#define TSW(ch, t) ((t) ^ ((((ch) >> 2) & 7) << 3))

// XOR swizzle for linear [128][32]-short LDS tiles staged by global_load_lds:
// physical short-offset <-> logical short-offset; XORs bits 3-4 (16B slot)
// with bits 7-8 (row bits 2-3). Involution. Makes the stride-32 column-slice
// ds_read_b128 exactly 2-way on banks (free) instead of 8-way.
static __device__ __forceinline__ int swz(int s) {
  return s ^ (((s >> 7) & 3) << 3);
}

// async global->LDS, 16B per lane. LDS dest = wave-uniform base + lane*16.
static __device__ __forceinline__ void gld16(const short* g, short* l) {
  __builtin_amdgcn_global_load_lds(
      (const __attribute__((address_space(1))) void*)g,
      (__attribute__((address_space(3))) void*)l, 16, 0, 0);
}

// ---------------------------------------------------------------------------
// xcvt: xb = bf16(x), one-time RNE conversion (identical f2bf as consumers).
// ---------------------------------------------------------------------------
__global__ __launch_bounds__(256)
void xcvt(const float* __restrict__ x, short* __restrict__ xb) {
  const int n8 = (B_ * N_ * C_) / 8;
  for (int i = blockIdx.x * 256 + threadIdx.x; i < n8; i += gridDim.x * 256) {
    const float4 a = *(const float4*)(x + (size_t)i * 8);
    const float4 b = *(const float4*)(x + (size_t)i * 8 + 4);
    *(s16x8*)(xb + (size_t)i * 8) = pack8(a, b);
  }
}

// ---------------------------------------------------------------------------
// gram_p: partial Gram. For pair tile (ti,tj) and token chunk s:
//   Gp[((b*21+pair)*NS+s)] (128x128 fp32) = sum_{n in chunk} X[n,i0+:]^T X[n,j0+:]
// 1D grid 672 = 8 XCD x 84, XCD-swizzled. BF=1: read pre-converted bf16 xb
// (half fetch, no cvt VALU); BF=0: legacy fp32 path.
// ---------------------------------------------------------------------------
template<int BF>
__global__ __launch_bounds__(256)
void gram_p(const float* __restrict__ x, const short* __restrict__ xb,
            float* __restrict__ Gp) {
  const int f = blockIdx.x;
  const int xcd = f & 7;
  const int t = f >> 3;            // 0..83
  const int pair = t % 21;
  const int cdiv = t / 21;         // 0..3
  const int c = xcd + 8 * cdiv;    // 0..31
  const int split = c & 3;
  const int b = c >> 2;

  int rem = pair, ti = 0;
#pragma unroll
  for (int it = 0; it < 5; ++it)
    if (rem >= 6 - ti) { rem -= 6 - ti; ++ti; }
  const int tj = ti + rem;
  const int i0 = ti * 128, j0 = tj * 128;
  const bool diag = (ti == tj);

  const int tid = threadIdx.x;
  const int lane = tid & 63, wave = tid >> 6;
  const int l15 = lane & 15, quad = lane >> 4;
  const int wm = wave & 1, wn = wave >> 1;

  __shared__ __align__(16) short smem[2 * 128 * 72];   // 36864 B
  short* At = smem;
  short* Bt = smem + 128 * 72;

  const int tg = tid >> 4;       // 0..15 -> t0 = 4*tg
  const int cg = tid & 15;       // 0..15
  const int t0 = tg * 4;
  const int c0 = cg * 4;         // BF=0 path
  const float* xbF = x + (size_t)b * N_ * C_;
  const short* xbB = xb + (size_t)b * N_ * C_;

  f32x4 acc[4][4] = {};

  const int nbeg = split * (N_ / NS_);
  const int nend = nbeg + (N_ / NS_);
  for (int n0 = nbeg; n0 < nend; n0 += 64) {
    if (BF) {
      s16x8 la[4], lb[4];
#pragma unroll
      for (int r = 0; r < 4; ++r)
        la[r] = *(const s16x8*)(xbB + (size_t)(n0 + t0 + r) * C_ + i0 + cg * 8);
      if (!diag) {
#pragma unroll
        for (int r = 0; r < 4; ++r)
          lb[r] = *(const s16x8*)(xbB + (size_t)(n0 + t0 + r) * C_ + j0 + cg * 8);
      }
      __syncthreads();
#pragma unroll
      for (int cc = 0; cc < 8; ++cc) {
        const int ch = cg * 8 + cc;
        s16x4 v;
        v[0] = la[0][cc]; v[1] = la[1][cc]; v[2] = la[2][cc]; v[3] = la[3][cc];
        *(s16x4*)&At[ch * 72 + TSW(ch, t0)] = v;
      }
      if (!diag) {
#pragma unroll
        for (int cc = 0; cc < 8; ++cc) {
          const int ch = cg * 8 + cc;
          s16x4 v;
          v[0] = lb[0][cc]; v[1] = lb[1][cc]; v[2] = lb[2][cc]; v[3] = lb[3][cc];
          *(s16x4*)&Bt[ch * 72 + TSW(ch, t0)] = v;
        }
      }
      __syncthreads();
    } else {
      float4 la[2][4], lb[2][4];
#pragma unroll
      for (int q = 0; q < 2; ++q)
#pragma unroll
        for (int r = 0; r < 4; ++r)
          la[q][r] = *(const float4*)(xbF + (size_t)(n0 + t0 + r) * C_ + i0 + c0 + q * 64);
      if (!diag) {
#pragma unroll
        for (int q = 0; q < 2; ++q)
#pragma unroll
          for (int r = 0; r < 4; ++r)
            lb[q][r] = *(const float4*)(xbF + (size_t)(n0 + t0 + r) * C_ + j0 + c0 + q * 64);
      }
      __syncthreads();
#pragma unroll
      for (int q = 0; q < 2; ++q)
#pragma unroll
        for (int cc = 0; cc < 4; ++cc) {
          const int ch = c0 + q * 64 + cc;
          s16x4 v;
          v[0] = f2bf(((const float*)&la[q][0])[cc]);
          v[1] = f2bf(((const float*)&la[q][1])[cc]);
          v[2] = f2bf(((const float*)&la[q][2])[cc]);
          v[3] = f2bf(((const float*)&la[q][3])[cc]);
          *(s16x4*)&At[ch * 72 + TSW(ch, t0)] = v;
        }
      if (!diag) {
#pragma unroll
        for (int q = 0; q < 2; ++q)
#pragma unroll
          for (int cc = 0; cc < 4; ++cc) {
            const int ch = c0 + q * 64 + cc;
            s16x4 v;
            v[0] = f2bf(((const float*)&lb[q][0])[cc]);
            v[1] = f2bf(((const float*)&lb[q][1])[cc]);
            v[2] = f2bf(((const float*)&lb[q][2])[cc]);
            v[3] = f2bf(((const float*)&lb[q][3])[cc]);
            *(s16x4*)&Bt[ch * 72 + TSW(ch, t0)] = v;
          }
      }
      __syncthreads();
    }
    const short* Bre = diag ? At : Bt;
#pragma unroll
    for (int ks = 0; ks < 64; ks += 32) {
      s16x8 af[4], bfr[4];
#pragma unroll
      for (int mi = 0; mi < 4; ++mi) {
        const int ch = wm * 64 + mi * 16 + l15;
        af[mi] = *(const s16x8*)&At[ch * 72 + TSW(ch, ks + quad * 8)];
      }
#pragma unroll
      for (int ni = 0; ni < 4; ++ni) {
        const int ch = wn * 64 + ni * 16 + l15;
        bfr[ni] = *(const s16x8*)&Bre[ch * 72 + TSW(ch, ks + quad * 8)];
      }
#pragma unroll
      for (int ni = 0; ni < 4; ++ni)
#pragma unroll
        for (int mi = 0; mi < 4; ++mi)
          acc[mi][ni] = __builtin_amdgcn_mfma_f32_16x16x32_bf16(af[mi], bfr[ni], acc[mi][ni], 0, 0, 0);
    }
    if (BF) __syncthreads();   // keep write/read phases separated (BF path has no trailing sync)
  }

  float* Gpb = Gp + (((size_t)b * 21 + pair) * NS_ + split) * (128 * 128);
#pragma unroll
  for (int mi = 0; mi < 4; ++mi)
#pragma unroll
    for (int ni = 0; ni < 4; ++ni) {
      const int ii = wm * 64 + mi * 16 + quad * 4;
      const int jj = wn * 64 + ni * 16 + l15;
#pragma unroll
      for (int r = 0; r < 4; ++r)
        Gpb[(ii + r) * 128 + jj] = acc[mi][ni][r];
    }
}

// ---------------------------------------------------------------------------
// gram_red: G tile = sum of NS_ fp32 partials -> bf16, write both triangles.
// ---------------------------------------------------------------------------
__global__ __launch_bounds__(256)
void gram_red(const float* __restrict__ Gp, short* __restrict__ G) {
  const int pair = blockIdx.x;
  int rem = pair, ti = 0;
#pragma unroll
  for (int it = 0; it < 5; ++it)
    if (rem >= 6 - ti) { rem -= 6 - ti; ++ti; }
  const int tj = ti + rem;
  const int b = blockIdx.y;
  const int i0 = ti * 128, j0 = tj * 128;
  const bool diag = (ti == tj);
  const int tid = threadIdx.x;

  __shared__ short Ts[128 * 137];    // 35072 B

  const float4* P = (const float4*)(Gp + (((size_t)b * 21 + pair) * NS_) * (128 * 128));
  short* Gb = G + (size_t)b * C_ * C_;

#pragma unroll
  for (int it = 0; it < 16; ++it) {
    const int q = tid + it * 256;          // float4 index 0..4095
    const int row = q >> 5;
    const int c4 = q & 31;
    float4 v = P[q];
    const float4 v1 = P[q + 4096];
    const float4 v2 = P[q + 8192];
    const float4 v3 = P[q + 12288];
    v.x += v1.x + v2.x + v3.x;
    v.y += v1.y + v2.y + v3.y;
    v.z += v1.z + v2.z + v3.z;
    v.w += v1.w + v2.w + v3.w;
    s16x4 sv;
    sv[0] = f2bf(v.x); sv[1] = f2bf(v.y); sv[2] = f2bf(v.z); sv[3] = f2bf(v.w);
    *(s16x4*)&Gb[(size_t)(i0 + row) * C_ + j0 + c4 * 4] = sv;
    if (!diag) {
#pragma unroll
      for (int c = 0; c < 4; ++c)
        Ts[(c4 * 4 + c) * 137 + row] = sv[c];
    }
  }
  if (!diag) {
    __syncthreads();
#pragma unroll
    for (int p = 0; p < 8; ++p) {
      const int id = tid + p * 256;        // 0..2047
      const int j = id >> 4, cs = (id & 15) * 8;
      *(s16x8*)&Gb[(size_t)(j0 + j) * C_ + i0 + cs] = *(const s16x8*)&Ts[j * 137 + cs];
    }
  }
}

// ---------------------------------------------------------------------------
// gemm_fb: Out[z][m][n] (bf16) = sum_k A[m][k] (fp32) * Bb[z][n][k] (bf16).
// NT-form MFMA GEMM. 128x128 tile, BK=32. B staged via global_load_lds into
// linear [128][32] LDS with swz; A reg-staged fp32->bf16 into padded LDS.
// ---------------------------------------------------------------------------
__global__ __launch_bounds__(256)
void gemm_fb(const float* __restrict__ A, const short* __restrict__ Bb,
             short* __restrict__ Out, size_t sB, size_t sO) {
  const int z = blockIdx.z;
  const int n0 = blockIdx.x * 128;
  const int m0 = blockIdx.y * 128;
  const int tid = threadIdx.x;
  const int lane = tid & 63, wave = tid >> 6;
  const int l15 = lane & 15, quad = lane >> 4;
  const int wm = wave & 1, wn = wave >> 1;

  __shared__ __align__(16) short As[128 * 40];
  __shared__ __align__(16) short Bs[128 * 32];

  const int ar = tid >> 1;
  const int ak = (tid & 1) * 16;
  const float* ap = A + (size_t)(m0 + ar) * C_ + ak;

  const short* bsrc[2];
  short* bdst[2];
#pragma unroll
  for (int cc = 0; cc < 2; ++cc) {
    const int P = wave * 1024 + cc * 512 + lane * 8;
    const int L = swz(P);
    bsrc[cc] = Bb + (size_t)z * sB + (size_t)(n0 + (L >> 5)) * C_ + (L & 31);
    bdst[cc] = &Bs[wave * 1024 + cc * 512];
  }

  f32x4 acc[4][4] = {};

  for (int k0 = 0; k0 < C_; k0 += 32) {
    const float4 a0 = *(const float4*)(ap + k0 + 0);
    const float4 a1 = *(const float4*)(ap + k0 + 4);
    const float4 a2 = *(const float4*)(ap + k0 + 8);
    const float4 a3 = *(const float4*)(ap + k0 + 12);
    __syncthreads();
#pragma unroll
    for (int cc = 0; cc < 2; ++cc) gld16(bsrc[cc] + k0, bdst[cc]);
    *(s16x8*)&As[ar * 40 + ak]     = pack8(a0, a1);
    *(s16x8*)&As[ar * 40 + ak + 8] = pack8(a2, a3);
    __syncthreads();
    s16x8 af[4];
#pragma unroll
    for (int mi = 0; mi < 4; ++mi)
      af[mi] = *(const s16x8*)&As[(wm * 64 + mi * 16 + l15) * 40 + quad * 8];
#pragma unroll
    for (int ni = 0; ni < 4; ++ni) {
      const s16x8 bf = *(const s16x8*)&Bs[swz((wn * 64 + ni * 16 + l15) * 32 + quad * 8)];
#pragma unroll
      for (int mi = 0; mi < 4; ++mi)
        acc[mi][ni] = __builtin_amdgcn_mfma_f32_16x16x32_bf16(af[mi], bf, acc[mi][ni], 0, 0, 0);
    }
  }

  short* ob = Out + (size_t)z * sO;
#pragma unroll
  for (int mi = 0; mi < 4; ++mi) {
    const int m = m0 + wm * 64 + mi * 16 + quad * 4;
#pragma unroll
    for (int ni = 0; ni < 4; ++ni) {
      const int n = n0 + wn * 64 + ni * 16 + l15;
#pragma unroll
      for (int r = 0; r < 4; ++r)
        ob[(size_t)(m + r) * C_ + n] = f2bf(acc[mi][ni][r]);
    }
  }
}

// ---------------------------------------------------------------------------
// row_norms: ||q_d||^2 = dot(Y[row], w_qkv[row]) since Y = W_qk G, G = X^T X.
// ---------------------------------------------------------------------------
__global__ __launch_bounds__(256)
void row_norms(const short* __restrict__ Y, const float* __restrict__ w_qkv,
               float* __restrict__ norms) {
  const int b = blockIdx.y;
  const int m = blockIdx.x * 4 + (threadIdx.x >> 6);   // 0..1535
  const int lane = threadIdx.x & 63;
  const short* y = Y + ((size_t)b * 1536 + m) * C_;
  const float* w = w_qkv + (size_t)m * C_;
  float s = 0.f;
#pragma unroll
  for (int j = 0; j < 3; ++j) {
    const int o = j * 256 + lane * 4;
    const s16x4 yv = *(const s16x4*)(y + o);
    const float4 wv = *(const float4*)(w + o);
    s += bf2f((unsigned short)yv[0]) * wv.x + bf2f((unsigned short)yv[1]) * wv.y +
         bf2f((unsigned short)yv[2]) * wv.z + bf2f((unsigned short)yv[3]) * wv.w;
  }
#pragma unroll
  for (int o = 32; o > 0; o >>= 1) s += __shfl_xor(s, o);
  if (lane == 0) {
    int idx;
    if (m < 768) idx = (b * 8 + m / 96) * 96 + (m % 96);
    else { const int mm = m - 768; idx = B_ * H_ * 96 + (b * 8 + mm / 96) * 96 + (mm % 96); }
    norms[idx] = s;
  }
}

// ---------------------------------------------------------------------------
// s_attn: per (b,h): S_raw = Yq_h @ Wk_h^T via MFMA (K=768), scale, softmax.
// ---------------------------------------------------------------------------
__global__ __launch_bounds__(256)
void s_attn(const short* __restrict__ Y, const float* __restrict__ w_qkv,
            const float* __restrict__ norms, const float* __restrict__ temp,
            float* __restrict__ S) {
  const int bh = blockIdx.x;
  const int b = bh >> 3, h = bh & 7;
  const int tid = threadIdx.x;
  const int lane = tid & 63, wave = tid >> 6;
  const int l15 = lane & 15, quad = lane >> 4;

  __shared__ __align__(16) float Sf[96 * 97];   // 37248 B; aliased as bf16 staging
  __shared__ float qsc[96], ksc[96];
  short* Ys = (short*)Sf;                // 96*72 shorts
  short* Ks = (short*)Sf + 96 * 72;      // 96*72 shorts

  if (tid < 96)
    qsc[tid] = temp[h] / fmaxf(sqrtf(norms[bh * 96 + tid]), EPSN);
  else if (tid < 192)
    ksc[tid - 96] = 1.0f / fmaxf(sqrtf(norms[B_ * H_ * 96 + bh * 96 + (tid - 96)]), EPSN);

  const short* yb = Y + ((size_t)b * 1536 + h * 96) * C_;
  const float* wk = w_qkv + (size_t)(C_ + h * 96) * C_;

  f32x4 sc[9] = {};
  for (int k0 = 0; k0 < C_; k0 += 64) {
    s16x8 yv[3];
    float4 wv[3][2];
#pragma unroll
    for (int j = 0; j < 3; ++j) {
      const int id = tid + j * 256;           // 0..767
      const int r = id >> 3, c8 = (id & 7) * 8;
      yv[j] = *(const s16x8*)(yb + (size_t)r * C_ + k0 + c8);
      wv[j][0] = *(const float4*)(wk + (size_t)r * C_ + k0 + c8);
      wv[j][1] = *(const float4*)(wk + (size_t)r * C_ + k0 + c8 + 4);
    }
    __syncthreads();
#pragma unroll
    for (int j = 0; j < 3; ++j) {
      const int id = tid + j * 256;
      const int r = id >> 3, c8 = (id & 7) * 8;
      *(s16x8*)&Ys[r * 72 + c8] = yv[j];
      *(s16x8*)&Ks[r * 72 + c8] = pack8(wv[j][0], wv[j][1]);
    }
    __syncthreads();
#pragma unroll
    for (int j = 0; j < 9; ++j) {
      const int t = wave * 9 + j, dt = t / 6, et = t % 6;
#pragma unroll
      for (int kk = 0; kk < 64; kk += 32) {
        const s16x8 a  = *(const s16x8*)&Ys[(dt * 16 + l15) * 72 + kk + quad * 8];
        const s16x8 bb = *(const s16x8*)&Ks[(et * 16 + l15) * 72 + kk + quad * 8];
        sc[j] = __builtin_amdgcn_mfma_f32_16x16x32_bf16(a, bb, sc[j], 0, 0, 0);
      }
    }
  }
  __syncthreads();
#pragma unroll
  for (int j = 0; j < 9; ++j) {
    const int t = wave * 9 + j, dt = t / 6, et = t % 6;
    const int e = et * 16 + l15;
    const float kf = ksc[e];
#pragma unroll
    for (int r = 0; r < 4; ++r) {
      const int d = dt * 16 + quad * 4 + r;
      Sf[d * 97 + e] = sc[j][r] * qsc[d] * kf;
    }
  }
  __syncthreads();
  float* Sb = S + (size_t)bh * (HD_ * HD_);
  for (int rr = 0; rr < 24; ++rr) {
    const int d = wave * 24 + rr;
    const float v0 = Sf[d * 97 + lane];
    const float v1 = (lane < 32) ? Sf[d * 97 + 64 + lane] : -1e30f;
    float mx = fmaxf(v0, v1);
#pragma unroll
    for (int o = 32; o > 0; o >>= 1) mx = fmaxf(mx, __shfl_xor(mx, o));
    const float e0 = __expf(v0 - mx);
    const float e1 = (lane < 32) ? __expf(v1 - mx) : 0.0f;
    float sum = e0 + e1;
#pragma unroll
    for (int o = 32; o > 0; o >>= 1) sum += __shfl_xor(sum, o);
    const float inv = 1.0f / sum;
    Sb[d * 96 + lane] = e0 * inv;
    if (lane < 32) Sb[d * 96 + 64 + lane] = e1 * inv;
  }
}

// ---------------------------------------------------------------------------
// av_gemm: AVt[b][c][h*96+d] (bf16) = sum_e attn[bh][d][e] * w_qkv[2C+h*96+e][c]
// ---------------------------------------------------------------------------
__global__ __launch_bounds__(256)
void av_gemm(const float* __restrict__ S, const float* __restrict__ w_qkv,
             short* __restrict__ AVt) {
  const int bh = blockIdx.x;
  const int b = bh >> 3, h = bh & 7;
  const int ct = blockIdx.y * 64;
  const int tid = threadIdx.x;
  __shared__ float at[96 * 97];
  __shared__ float wv[96 * 64];
  const float* Sb = S + (size_t)bh * (HD_ * HD_);
  for (int i = tid; i < 96 * 96; i += 256)
    at[(i / 96) * 97 + (i % 96)] = Sb[i];
  for (int i = tid; i < 96 * 64; i += 256) {
    const int e = i >> 6, c = i & 63;
    wv[e * 64 + c] = w_qkv[(size_t)(2 * C_ + h * 96 + e) * C_ + ct + c];
  }
  __syncthreads();
  const int d0 = (tid >> 4) * 6;
  const int c0 = (tid & 15) * 4;
  float acc[6][4] = {};
  for (int e = 0; e < 96; ++e) {
    const float4 bv = *(const float4*)&wv[e * 64 + c0];
    float aa[6];
#pragma unroll
    for (int i = 0; i < 6; ++i) aa[i] = at[(d0 + i) * 97 + e];
#pragma unroll
    for (int i = 0; i < 6; ++i) {
      acc[i][0] += aa[i] * bv.x; acc[i][1] += aa[i] * bv.y;
      acc[i][2] += aa[i] * bv.z; acc[i][3] += aa[i] * bv.w;
    }
  }
  short* AVb = AVt + (size_t)b * C_ * C_;
#pragma unroll
  for (int i = 0; i < 6; ++i)
#pragma unroll
    for (int j = 0; j < 4; ++j)
      AVb[(size_t)(ct + c0 + j) * C_ + h * 96 + d0 + i] = f2bf(acc[i][j]);
}

// ---------------------------------------------------------------------------
// gemm_xm_bf: out[z][m][n] = sum_k xb[z][m][k]*Mb[z][n][k] + bias[n].
// m97-style: both operands via global_load_lds dwordx4 into linear [128][32]
// LDS with swz (inverse-swizzled source + swizzled read). XCD-swizzled grid.
// ---------------------------------------------------------------------------
__global__ __launch_bounds__(256)
void gemm_xm_bf(const short* __restrict__ xb, const short* __restrict__ Mb,
                const float* __restrict__ bias, float* __restrict__ out) {
  const int f = blockIdx.x;
  const int xcd = f & 7;
  const int t = f >> 3;           // 0..191
  const int j6 = t % 6;           // n-block (fast within XCD)
  const int sdiv = t / 6;         // 0..31
  const int s = xcd + 8 * sdiv;   // 0..255 (m-slice id)
  const int z = s >> 5;
  const int n0 = j6 * 128;
  const int m0 = (s & 31) * 128;
  const int tid = threadIdx.x;
  const int lane = tid & 63;
  const int wave = tid >> 6;
  const int l15 = lane & 15;
  const int quad = lane >> 4;
  const int wm = wave & 1;
  const int wn = wave >> 1;

  __shared__ __align__(16) short As[128 * 32];
  __shared__ __align__(16) short Bs[128 * 32];

  const short* asrc[2]; const short* bsrc[2];
  short* adst[2]; short* bdst[2];
#pragma unroll
  for (int cc = 0; cc < 2; ++cc) {
    const int P = wave * 1024 + cc * 512 + lane * 8;   // physical short offset
    const int L = swz(P);                               // logical (row,col)
    const int row = L >> 5, col = L & 31;
    asrc[cc] = xb + ((size_t)z * N_ + m0 + row) * C_ + col;
    bsrc[cc] = Mb + (size_t)z * C_ * C_ + (size_t)(n0 + row) * C_ + col;
    adst[cc] = &As[wave * 1024 + cc * 512];
    bdst[cc] = &Bs[wave * 1024 + cc * 512];
  }

  f32x4 acc[4][4] = {};

  for (int k0 = 0; k0 < C_; k0 += 32) {
    __syncthreads();             // previous iter's LDS reads complete
#pragma unroll
    for (int cc = 0; cc < 2; ++cc) {
      gld16(asrc[cc] + k0, adst[cc]);
      gld16(bsrc[cc] + k0, bdst[cc]);
    }
    __syncthreads();             // compiler drains vmcnt before barrier
    s16x8 af[4];
#pragma unroll
    for (int mi = 0; mi < 4; ++mi)
      af[mi] = *(const s16x8*)&As[swz((wm * 64 + mi * 16 + l15) * 32 + quad * 8)];
#pragma unroll
    for (int ni = 0; ni < 4; ++ni) {
      const s16x8 bf = *(const s16x8*)&Bs[swz((wn * 64 + ni * 16 + l15) * 32 + quad * 8)];
#pragma unroll
      for (int mi = 0; mi < 4; ++mi)
        acc[mi][ni] = __builtin_amdgcn_mfma_f32_16x16x32_bf16(af[mi], bf, acc[mi][ni], 0, 0, 0);
    }
  }

  float bv[4];
#pragma unroll
  for (int ni = 0; ni < 4; ++ni) bv[ni] = bias[n0 + wn * 64 + ni * 16 + l15];
#pragma unroll
  for (int mi = 0; mi < 4; ++mi) {
    const int m = m0 + wm * 64 + mi * 16 + quad * 4;
#pragma unroll
    for (int ni = 0; ni < 4; ++ni) {
      const int n = n0 + wn * 64 + ni * 16 + l15;
      float* dst = out + ((size_t)z * N_ + m) * C_ + n;
#pragma unroll
      for (int r = 0; r < 4; ++r)
        dst[(size_t)r * C_] = acc[mi][ni][r] + bv[ni];
    }
  }
}

// ---------------------------------------------------------------------------
// gemm_xm_f32: legacy fp32-x variant (tier-3 fallback, identical to R3).
// ---------------------------------------------------------------------------
__global__ __launch_bounds__(256)
void gemm_xm_f32(const float* __restrict__ x, const short* __restrict__ Mb,
                 const float* __restrict__ bias, float* __restrict__ out) {
  const int f = blockIdx.x;
  const int xcd = f & 7;
  const int t = f >> 3;
  const int j6 = t % 6;
  const int sdiv = t / 6;
  const int s = xcd + 8 * sdiv;
  const int z = s >> 5;
  const int n0 = j6 * 128;
  const int m0 = (s & 31) * 128;
  const int tid = threadIdx.x;
  const int lane = tid & 63;
  const int wave = tid >> 6;
  const int l15 = lane & 15;
  const int quad = lane >> 4;
  const int wm = wave & 1;
  const int wn = wave >> 1;

  __shared__ __align__(16) short As[128 * 40];
  __shared__ __align__(16) short Bs[128 * 40];

  const int ar = tid >> 1;
  const int ak = (tid & 1) * 16;
  const float* xp = x + ((size_t)z * N_ + m0 + ar) * C_ + ak;
  const short* mp = Mb + (size_t)z * C_ * C_ + (size_t)(n0 + ar) * C_ + ak;

  f32x4 acc[4][4] = {};

  for (int k0 = 0; k0 < C_; k0 += 32) {
    const float4 a0 = *(const float4*)(xp + k0 + 0);
    const float4 a1 = *(const float4*)(xp + k0 + 4);
    const float4 a2 = *(const float4*)(xp + k0 + 8);
    const float4 a3 = *(const float4*)(xp + k0 + 12);
    const s16x8 b0 = *(const s16x8*)(mp + k0 + 0);
    const s16x8 b1 = *(const s16x8*)(mp + k0 + 8);
    __syncthreads();
    *(s16x8*)&As[ar * 40 + ak]     = pack8(a0, a1);
    *(s16x8*)&As[ar * 40 + ak + 8] = pack8(a2, a3);
    *(s16x8*)&Bs[ar * 40 + ak]     = b0;
    *(s16x8*)&Bs[ar * 40 + ak + 8] = b1;
    __syncthreads();
    s16x8 af[4];
#pragma unroll
    for (int mi = 0; mi < 4; ++mi)
      af[mi] = *(const s16x8*)&As[(wm * 64 + mi * 16 + l15) * 40 + quad * 8];
#pragma unroll
    for (int ni = 0; ni < 4; ++ni) {
      const s16x8 bf = *(const s16x8*)&Bs[(wn * 64 + ni * 16 + l15) * 40 + quad * 8];
#pragma unroll
      for (int mi = 0; mi < 4; ++mi)
        acc[mi][ni] = __builtin_amdgcn_mfma_f32_16x16x32_bf16(af[mi], bf, acc[mi][ni], 0, 0, 0);
    }
  }

  float bv[4];
#pragma unroll
  for (int ni = 0; ni < 4; ++ni) bv[ni] = bias[n0 + wn * 64 + ni * 16 + l15];
#pragma unroll
  for (int mi = 0; mi < 4; ++mi) {
    const int m = m0 + wm * 64 + mi * 16 + quad * 4;
#pragma unroll
    for (int ni = 0; ni < 4; ++ni) {
      const int n = n0 + wn * 64 + ni * 16 + l15;
      float* dst = out + ((size_t)z * N_ + m) * C_ + n;
#pragma unroll
      for (int r = 0; r < 4; ++r)
        dst[(size_t)r * C_] = acc[mi][ni][r] + bv[ni];
    }
  }
}

// ---------------------------------------------------------------------------
extern "C" void kernel_launch(void* const* d_in, const int* in_sizes, int n_in,
                              void* d_out, int out_size, void* d_ws, size_t ws_size,
                              hipStream_t stream) {
  const float* x      = (const float*)d_in[0];
  const float* w_qkv  = (const float*)d_in[1];
  const float* temp   = (const float*)d_in[2];
  const float* w_proj = (const float*)d_in[3];
  const float* b_proj = (const float*)d_in[4];
  float* out = (float*)d_out;

  // Fixed region (byte offsets from ws base):
  //   S     @ 0         : 2359296 B  (fp32 attn)     [s_attn .. av_gemm]
  //   norms @ 2359296   : 49152 B
  //   G/AVt @ 2408448   : 9437184 B  (bf16)
  //   Mb    @ 11845632  : 9437184 B  (bf16)
  //   Y     @ 21282816  : 18874368 B (bf16) -> ends 40157184
  // Tier 1 (ws >= 106.3 MB): Gp @ 11845632 (44 MB, overlaps Mb+Y, dead
  //   before they're written); xb @ 55885824 (50.3 MB). xcvt first.
  // Tier 2 (ws >= 90.5 MB): Gp and xb both @ 40157184 (Gp dead before xcvt).
  // Tier 3: R3 layout, fp32 path everywhere.
  char* base = (char*)d_ws;
  float* S     = (float*)base;
  float* norms = (float*)(base + 2359296);
  short* G     = (short*)(base + 2408448);
  short* AVt   = G;
  short* Mb    = (short*)(base + 11845632);
  short* Y     = (short*)(base + 21282816);

  const size_t need1 = 55885824 + 50331648;   // 106217472
  const size_t need2 = 40157184 + 50331648;   // 90488832
  const int tier = (ws_size >= need1) ? 1 : (ws_size >= need2) ? 2 : 3;

  float* Gp = (tier == 2) ? (float*)(base + 40157184) : (float*)(base + 11845632);
  short* xb = (tier == 1) ? (short*)(base + 55885824)
            : (tier == 2) ? (short*)(base + 40157184) : nullptr;

  if (tier == 1) {
    xcvt<<<3072, 256, 0, stream>>>(x, xb);
    gram_p<1><<<21 * NS_ * B_, 256, 0, stream>>>(x, xb, Gp);
  } else {
    gram_p<0><<<21 * NS_ * B_, 256, 0, stream>>>(x, xb ? xb : (const short*)G, Gp);
  }

  gram_red<<<dim3(21, B_), 256, 0, stream>>>(Gp, G);

  if (tier == 2) xcvt<<<3072, 256, 0, stream>>>(x, xb);

  // Y_b = W_qk @ G_b   (G symmetric -> NT form)
  gemm_fb<<<dim3(C_ / 128, 1536 / 128, B_), 256, 0, stream>>>(
      w_qkv, G, Y, (size_t)C_ * C_, (size_t)1536 * C_);

  row_norms<<<dim3(1536 / 4, B_), 256, 0, stream>>>(Y, w_qkv, norms);

  s_attn<<<B_ * H_, 256, 0, stream>>>(Y, w_qkv, norms, temp, S);

  av_gemm<<<dim3(B_ * H_, C_ / 64), 256, 0, stream>>>(S, w_qkv, AVt);

  gemm_fb<<<dim3(C_ / 128, C_ / 128, B_), 256, 0, stream>>>(
      w_proj, AVt, Mb, (size_t)C_ * C_, (size_t)C_ * C_);

  if (tier == 3)
    gemm_xm_f32<<<C_ / 128 * (N_ / 128) * B_, 256, 0, stream>>>(x, Mb, b_proj, out);
  else
    gemm_xm_bf<<<C_ / 128 * (N_ / 128) * B_, 256, 0, stream>>>(xb, Mb, b_proj, out);
}

// Round 5
// 399.087 us; speedup vs baseline: 1.7213x; 1.0790x over previous
//
#include <hip/hip_runtime.h>
#include <cstdint>
#include <cstddef>

#define B_ 8
#define N_ 4096
#define C_ 768
#define H_ 8
#define HD_ 96
#define EPSN 1e-12f
#define NS_ 4          // gram split-K factor over tokens

typedef short s16x8 __attribute__((ext_vector_type(8)));   // 8 bf16 (4 VGPRs)
typedef short s16x4 __attribute__((ext_vector_type(4)));
typedef float f32x4 __attribute__((ext_vector_type(4)));   // MFMA acc

// fp32 -> bf16 (RNE) as raw short bits
static __device__ __forceinline__ short f2bf(float f) {
  unsigned u = __float_as_uint(f);
  unsigned r = (u + 0x7fff + ((u >> 16) & 1)) >> 16;
  return (short)r;
}
static __device__ __forceinline__ float bf2f(unsigned short s) {
  return __uint_as_float(((unsigned)s) << 16);
}
static __device__ __forceinline__ s16x8 pack8(const float4 a, const float4 b) {
  s16x8 r;
  r[0] = f2bf(a.x); r[1] = f2bf(a.y); r[2] = f2bf(a.z); r[3] = f2bf(a.w);
  r[4] = f2bf(b.x); r[5] = f2bf(b.y); r[6] = f2bf(b.z); r[7] = f2bf(b.w);
  return r;
}

// token-index swizzle for transposed LDS staging (gram)
#define TSW(ch, t) ((t) ^ ((((ch) >> 2) & 7) << 3))

// XOR swizzle for linear [128][32]-short LDS tiles staged by global_load_lds:
// involution on short offsets; XORs bits 3-4 (16B slot) with bits 7-8 (row
// bits 2-3) -> stride-32 column-slice ds_read_b128 is 2-way on banks (free).
static __device__ __forceinline__ int swz(int s) {
  return s ^ (((s >> 7) & 3) << 3);
}

// async global->LDS, 16B per lane. LDS dest = wave-uniform base + lane*16.
static __device__ __forceinline__ void gld16(const short* g, short* l) {
  __builtin_amdgcn_global_load_lds(
      (const __attribute__((address_space(1))) void*)g,
      (__attribute__((address_space(3))) void*)l, 16, 0, 0);
}

// ---------------------------------------------------------------------------
// xcvt: xb = bf16(x), one-time RNE conversion (identical f2bf as consumers).
// ---------------------------------------------------------------------------
__global__ __launch_bounds__(256)
void xcvt(const float* __restrict__ x, short* __restrict__ xb) {
  const int n8 = (B_ * N_ * C_) / 8;
  for (int i = blockIdx.x * 256 + threadIdx.x; i < n8; i += gridDim.x * 256) {
    const float4 a = *(const float4*)(x + (size_t)i * 8);
    const float4 b = *(const float4*)(x + (size_t)i * 8 + 4);
    *(s16x8*)(xb + (size_t)i * 8) = pack8(a, b);
  }
}

// ---------------------------------------------------------------------------
// wcvt: wb = bf16(w_qkv rows 0..1535)  (q+k blocks; v stays fp32 for av_gemm)
// ---------------------------------------------------------------------------
__global__ __launch_bounds__(256)
void wcvt(const float* __restrict__ w, short* __restrict__ wb) {
  const int i = blockIdx.x * 256 + threadIdx.x;     // 147456 = 1536*768/8
  const float4 a = *(const float4*)(w + (size_t)i * 8);
  const float4 b = *(const float4*)(w + (size_t)i * 8 + 4);
  *(s16x8*)(wb + (size_t)i * 8) = pack8(a, b);
}

// ---------------------------------------------------------------------------
// gram_p: partial Gram, split-K over tokens, XCD-swizzled 1D grid (672).
// BF=1: bf16 xb input; BF=0: fp32 fallback. 2 barriers per K-step.
// ---------------------------------------------------------------------------
template<int BF>
__global__ __launch_bounds__(256)
void gram_p(const float* __restrict__ x, const short* __restrict__ xb,
            float* __restrict__ Gp) {
  const int f = blockIdx.x;
  const int xcd = f & 7;
  const int t = f >> 3;            // 0..83
  const int pair = t % 21;
  const int cdiv = t / 21;         // 0..3
  const int c = xcd + 8 * cdiv;    // 0..31
  const int split = c & 3;
  const int b = c >> 2;

  int rem = pair, ti = 0;
#pragma unroll
  for (int it = 0; it < 5; ++it)
    if (rem >= 6 - ti) { rem -= 6 - ti; ++ti; }
  const int tj = ti + rem;
  const int i0 = ti * 128, j0 = tj * 128;
  const bool diag = (ti == tj);

  const int tid = threadIdx.x;
  const int lane = tid & 63, wave = tid >> 6;
  const int l15 = lane & 15, quad = lane >> 4;
  const int wm = wave & 1, wn = wave >> 1;

  __shared__ __align__(16) short smem[2 * 128 * 72];   // 36864 B
  short* At = smem;
  short* Bt = smem + 128 * 72;

  const int tg = tid >> 4;
  const int cg = tid & 15;
  const int t0 = tg * 4;
  const int c0 = cg * 4;
  const float* xbF = x + (size_t)b * N_ * C_;
  const short* xbB = xb + (size_t)b * N_ * C_;

  f32x4 acc[4][4] = {};

  const int nbeg = split * (N_ / NS_);
  const int nend = nbeg + (N_ / NS_);
  for (int n0 = nbeg; n0 < nend; n0 += 64) {
    if (BF) {
      s16x8 la[4], lb[4];
#pragma unroll
      for (int r = 0; r < 4; ++r)
        la[r] = *(const s16x8*)(xbB + (size_t)(n0 + t0 + r) * C_ + i0 + cg * 8);
      if (!diag) {
#pragma unroll
        for (int r = 0; r < 4; ++r)
          lb[r] = *(const s16x8*)(xbB + (size_t)(n0 + t0 + r) * C_ + j0 + cg * 8);
      }
      __syncthreads();
#pragma unroll
      for (int cc = 0; cc < 8; ++cc) {
        const int ch = cg * 8 + cc;
        s16x4 v;
        v[0] = la[0][cc]; v[1] = la[1][cc]; v[2] = la[2][cc]; v[3] = la[3][cc];
        *(s16x4*)&At[ch * 72 + TSW(ch, t0)] = v;
      }
      if (!diag) {
#pragma unroll
        for (int cc = 0; cc < 8; ++cc) {
          const int ch = cg * 8 + cc;
          s16x4 v;
          v[0] = lb[0][cc]; v[1] = lb[1][cc]; v[2] = lb[2][cc]; v[3] = lb[3][cc];
          *(s16x4*)&Bt[ch * 72 + TSW(ch, t0)] = v;
        }
      }
      __syncthreads();
    } else {
      float4 la[2][4], lb[2][4];
#pragma unroll
      for (int q = 0; q < 2; ++q)
#pragma unroll
        for (int r = 0; r < 4; ++r)
          la[q][r] = *(const float4*)(xbF + (size_t)(n0 + t0 + r) * C_ + i0 + c0 + q * 64);
      if (!diag) {
#pragma unroll
        for (int q = 0; q < 2; ++q)
#pragma unroll
          for (int r = 0; r < 4; ++r)
            lb[q][r] = *(const float4*)(xbF + (size_t)(n0 + t0 + r) * C_ + j0 + c0 + q * 64);
      }
      __syncthreads();
#pragma unroll
      for (int q = 0; q < 2; ++q)
#pragma unroll
        for (int cc = 0; cc < 4; ++cc) {
          const int ch = c0 + q * 64 + cc;
          s16x4 v;
          v[0] = f2bf(((const float*)&la[q][0])[cc]);
          v[1] = f2bf(((const float*)&la[q][1])[cc]);
          v[2] = f2bf(((const float*)&la[q][2])[cc]);
          v[3] = f2bf(((const float*)&la[q][3])[cc]);
          *(s16x4*)&At[ch * 72 + TSW(ch, t0)] = v;
        }
      if (!diag) {
#pragma unroll
        for (int q = 0; q < 2; ++q)
#pragma unroll
          for (int cc = 0; cc < 4; ++cc) {
            const int ch = c0 + q * 64 + cc;
            s16x4 v;
            v[0] = f2bf(((const float*)&lb[q][0])[cc]);
            v[1] = f2bf(((const float*)&lb[q][1])[cc]);
            v[2] = f2bf(((const float*)&lb[q][2])[cc]);
            v[3] = f2bf(((const float*)&lb[q][3])[cc]);
            *(s16x4*)&Bt[ch * 72 + TSW(ch, t0)] = v;
          }
      }
      __syncthreads();
    }
    const short* Bre = diag ? At : Bt;
#pragma unroll
    for (int ks = 0; ks < 64; ks += 32) {
      s16x8 af[4], bfr[4];
#pragma unroll
      for (int mi = 0; mi < 4; ++mi) {
        const int ch = wm * 64 + mi * 16 + l15;
        af[mi] = *(const s16x8*)&At[ch * 72 + TSW(ch, ks + quad * 8)];
      }
#pragma unroll
      for (int ni = 0; ni < 4; ++ni) {
        const int ch = wn * 64 + ni * 16 + l15;
        bfr[ni] = *(const s16x8*)&Bre[ch * 72 + TSW(ch, ks + quad * 8)];
      }
#pragma unroll
      for (int ni = 0; ni < 4; ++ni)
#pragma unroll
        for (int mi = 0; mi < 4; ++mi)
          acc[mi][ni] = __builtin_amdgcn_mfma_f32_16x16x32_bf16(af[mi], bfr[ni], acc[mi][ni], 0, 0, 0);
    }
  }

  float* Gpb = Gp + (((size_t)b * 21 + pair) * NS_ + split) * (128 * 128);
#pragma unroll
  for (int mi = 0; mi < 4; ++mi)
#pragma unroll
    for (int ni = 0; ni < 4; ++ni) {
      const int ii = wm * 64 + mi * 16 + quad * 4;
      const int jj = wn * 64 + ni * 16 + l15;
#pragma unroll
      for (int r = 0; r < 4; ++r)
        Gpb[(ii + r) * 128 + jj] = acc[mi][ni][r];
    }
}

// ---------------------------------------------------------------------------
// gram_red: G tile = sum of NS_ fp32 partials -> bf16, both triangles.
// ---------------------------------------------------------------------------
__global__ __launch_bounds__(256)
void gram_red(const float* __restrict__ Gp, short* __restrict__ G) {
  const int pair = blockIdx.x;
  int rem = pair, ti = 0;
#pragma unroll
  for (int it = 0; it < 5; ++it)
    if (rem >= 6 - ti) { rem -= 6 - ti; ++ti; }
  const int tj = ti + rem;
  const int b = blockIdx.y;
  const int i0 = ti * 128, j0 = tj * 128;
  const bool diag = (ti == tj);
  const int tid = threadIdx.x;

  __shared__ short Ts[128 * 137];    // 35072 B

  const float4* P = (const float4*)(Gp + (((size_t)b * 21 + pair) * NS_) * (128 * 128));
  short* Gb = G + (size_t)b * C_ * C_;

#pragma unroll
  for (int it = 0; it < 16; ++it) {
    const int q = tid + it * 256;
    const int row = q >> 5;
    const int c4 = q & 31;
    float4 v = P[q];
    const float4 v1 = P[q + 4096];
    const float4 v2 = P[q + 8192];
    const float4 v3 = P[q + 12288];
    v.x += v1.x + v2.x + v3.x;
    v.y += v1.y + v2.y + v3.y;
    v.z += v1.z + v2.z + v3.z;
    v.w += v1.w + v2.w + v3.w;
    s16x4 sv;
    sv[0] = f2bf(v.x); sv[1] = f2bf(v.y); sv[2] = f2bf(v.z); sv[3] = f2bf(v.w);
    *(s16x4*)&Gb[(size_t)(i0 + row) * C_ + j0 + c4 * 4] = sv;
    if (!diag) {
#pragma unroll
      for (int c = 0; c < 4; ++c)
        Ts[(c4 * 4 + c) * 137 + row] = sv[c];
    }
  }
  if (!diag) {
    __syncthreads();
#pragma unroll
    for (int p = 0; p < 8; ++p) {
      const int id = tid + p * 256;
      const int j = id >> 4, cs = (id & 15) * 8;
      *(s16x8*)&Gb[(size_t)(j0 + j) * C_ + i0 + cs] = *(const s16x8*)&Ts[j * 137 + cs];
    }
  }
}

// ---------------------------------------------------------------------------
// gemm_nt_bf: Out[z][m][n] (bf16) = sum_k A[m][k] * Bb[z][n][k], both bf16.
// 2-phase double-buffered gld16 pipeline, 1 barrier per K-step.
// Used for Y = wb[0:1536] @ G (G symmetric -> NT form).
// ---------------------------------------------------------------------------
__global__ __launch_bounds__(256)
void gemm_nt_bf(const short* __restrict__ A, const short* __restrict__ Bb,
                short* __restrict__ Out, size_t sB, size_t sO) {
  const int z = blockIdx.z;
  const int n0 = blockIdx.x * 128;
  const int m0 = blockIdx.y * 128;
  const int tid = threadIdx.x;
  const int lane = tid & 63, wave = tid >> 6;
  const int l15 = lane & 15, quad = lane >> 4;
  const int wm = wave & 1, wn = wave >> 1;

  __shared__ __align__(16) short As[2][128 * 32];
  __shared__ __align__(16) short Bs[2][128 * 32];

  const short* asrc[2]; const short* bsrc[2];
  int doff[2];
#pragma unroll
  for (int cc = 0; cc < 2; ++cc) {
    const int P = wave * 1024 + cc * 512 + lane * 8;
    const int L = swz(P);
    const int row = L >> 5, col = L & 31;
    asrc[cc] = A + (size_t)(m0 + row) * C_ + col;
    bsrc[cc] = Bb + (size_t)z * sB + (size_t)(n0 + row) * C_ + col;
    doff[cc] = wave * 1024 + cc * 512;
  }

  f32x4 acc[4][4] = {};

#pragma unroll
  for (int cc = 0; cc < 2; ++cc) {
    gld16(asrc[cc], &As[0][doff[cc]]);
    gld16(bsrc[cc], &Bs[0][doff[cc]]);
  }
  __syncthreads();
  int cur = 0;
  for (int k0 = 0; k0 < C_; k0 += 32) {
    const int nx = k0 + 32;
    if (nx < C_) {
#pragma unroll
      for (int cc = 0; cc < 2; ++cc) {
        gld16(asrc[cc] + nx, &As[cur ^ 1][doff[cc]]);
        gld16(bsrc[cc] + nx, &Bs[cur ^ 1][doff[cc]]);
      }
    }
    s16x8 af[4];
#pragma unroll
    for (int mi = 0; mi < 4; ++mi)
      af[mi] = *(const s16x8*)&As[cur][swz((wm * 64 + mi * 16 + l15) * 32 + quad * 8)];
#pragma unroll
    for (int ni = 0; ni < 4; ++ni) {
      const s16x8 bf = *(const s16x8*)&Bs[cur][swz((wn * 64 + ni * 16 + l15) * 32 + quad * 8)];
#pragma unroll
      for (int mi = 0; mi < 4; ++mi)
        acc[mi][ni] = __builtin_amdgcn_mfma_f32_16x16x32_bf16(af[mi], bf, acc[mi][ni], 0, 0, 0);
    }
    __syncthreads();
    cur ^= 1;
  }

  short* ob = Out + (size_t)z * sO;
#pragma unroll
  for (int mi = 0; mi < 4; ++mi) {
    const int m = m0 + wm * 64 + mi * 16 + quad * 4;
#pragma unroll
    for (int ni = 0; ni < 4; ++ni) {
      const int n = n0 + wn * 64 + ni * 16 + l15;
#pragma unroll
      for (int r = 0; r < 4; ++r)
        ob[(size_t)(m + r) * C_ + n] = f2bf(acc[mi][ni][r]);
    }
  }
}

// ---------------------------------------------------------------------------
// gemm_fb: Out[z][m][n] (bf16) = sum_k A[m][k] (fp32) * Bb[z][n][k] (bf16).
// 2-phase: B dbuf via gld16; A dbuf via reg->pack8->LDS. 1 barrier/K-step.
// Used for Mb = w_proj @ AVt.
// ---------------------------------------------------------------------------
__global__ __launch_bounds__(256)
void gemm_fb(const float* __restrict__ A, const short* __restrict__ Bb,
             short* __restrict__ Out, size_t sB, size_t sO) {
  const int z = blockIdx.z;
  const int n0 = blockIdx.x * 128;
  const int m0 = blockIdx.y * 128;
  const int tid = threadIdx.x;
  const int lane = tid & 63, wave = tid >> 6;
  const int l15 = lane & 15, quad = lane >> 4;
  const int wm = wave & 1, wn = wave >> 1;

  __shared__ __align__(16) short As[2][128 * 40];
  __shared__ __align__(16) short Bs[2][128 * 32];

  const int ar = tid >> 1;
  const int ak = (tid & 1) * 16;
  const float* ap = A + (size_t)(m0 + ar) * C_ + ak;

  const short* bsrc[2];
  int doff[2];
#pragma unroll
  for (int cc = 0; cc < 2; ++cc) {
    const int P = wave * 1024 + cc * 512 + lane * 8;
    const int L = swz(P);
    bsrc[cc] = Bb + (size_t)z * sB + (size_t)(n0 + (L >> 5)) * C_ + (L & 31);
    doff[cc] = wave * 1024 + cc * 512;
  }

  f32x4 acc[4][4] = {};

  // prologue: stage k0=0 into buf 0
  {
    const float4 a0 = *(const float4*)(ap + 0);
    const float4 a1 = *(const float4*)(ap + 4);
    const float4 a2 = *(const float4*)(ap + 8);
    const float4 a3 = *(const float4*)(ap + 12);
#pragma unroll
    for (int cc = 0; cc < 2; ++cc) gld16(bsrc[cc], &Bs[0][doff[cc]]);
    *(s16x8*)&As[0][ar * 40 + ak]     = pack8(a0, a1);
    *(s16x8*)&As[0][ar * 40 + ak + 8] = pack8(a2, a3);
  }
  __syncthreads();
  int cur = 0;
  for (int k0 = 0; k0 < C_; k0 += 32) {
    const int nx = k0 + 32;
    float4 a0, a1, a2, a3;
    if (nx < C_) {
      a0 = *(const float4*)(ap + nx + 0);
      a1 = *(const float4*)(ap + nx + 4);
      a2 = *(const float4*)(ap + nx + 8);
      a3 = *(const float4*)(ap + nx + 12);
#pragma unroll
      for (int cc = 0; cc < 2; ++cc) gld16(bsrc[cc] + nx, &Bs[cur ^ 1][doff[cc]]);
    }
    s16x8 af[4];
#pragma unroll
    for (int mi = 0; mi < 4; ++mi)
      af[mi] = *(const s16x8*)&As[cur][(wm * 64 + mi * 16 + l15) * 40 + quad * 8];
#pragma unroll
    for (int ni = 0; ni < 4; ++ni) {
      const s16x8 bf = *(const s16x8*)&Bs[cur][swz((wn * 64 + ni * 16 + l15) * 32 + quad * 8)];
#pragma unroll
      for (int mi = 0; mi < 4; ++mi)
        acc[mi][ni] = __builtin_amdgcn_mfma_f32_16x16x32_bf16(af[mi], bf, acc[mi][ni], 0, 0, 0);
    }
    if (nx < C_) {
      *(s16x8*)&As[cur ^ 1][ar * 40 + ak]     = pack8(a0, a1);
      *(s16x8*)&As[cur ^ 1][ar * 40 + ak + 8] = pack8(a2, a3);
    }
    __syncthreads();
    cur ^= 1;
  }

  short* ob = Out + (size_t)z * sO;
#pragma unroll
  for (int mi = 0; mi < 4; ++mi) {
    const int m = m0 + wm * 64 + mi * 16 + quad * 4;
#pragma unroll
    for (int ni = 0; ni < 4; ++ni) {
      const int n = n0 + wn * 64 + ni * 16 + l15;
#pragma unroll
      for (int r = 0; r < 4; ++r)
        ob[(size_t)(m + r) * C_ + n] = f2bf(acc[mi][ni][r]);
    }
  }
}

// ---------------------------------------------------------------------------
// row_norms: ||q_d||^2 = dot(Y[row], w_qkv[row]) since Y = W_qk G, G = X^T X.
// ---------------------------------------------------------------------------
__global__ __launch_bounds__(256)
void row_norms(const short* __restrict__ Y, const float* __restrict__ w_qkv,
               float* __restrict__ norms) {
  const int b = blockIdx.y;
  const int m = blockIdx.x * 4 + (threadIdx.x >> 6);   // 0..1535
  const int lane = threadIdx.x & 63;
  const short* y = Y + ((size_t)b * 1536 + m) * C_;
  const float* w = w_qkv + (size_t)m * C_;
  float s = 0.f;
#pragma unroll
  for (int j = 0; j < 3; ++j) {
    const int o = j * 256 + lane * 4;
    const s16x4 yv = *(const s16x4*)(y + o);
    const float4 wv = *(const float4*)(w + o);
    s += bf2f((unsigned short)yv[0]) * wv.x + bf2f((unsigned short)yv[1]) * wv.y +
         bf2f((unsigned short)yv[2]) * wv.z + bf2f((unsigned short)yv[3]) * wv.w;
  }
#pragma unroll
  for (int o = 32; o > 0; o >>= 1) s += __shfl_xor(s, o);
  if (lane == 0) {
    int idx;
    if (m < 768) idx = (b * 8 + m / 96) * 96 + (m % 96);
    else { const int mm = m - 768; idx = B_ * H_ * 96 + (b * 8 + mm / 96) * 96 + (mm % 96); }
    norms[idx] = s;
  }
}

// ---------------------------------------------------------------------------
// s_attn: per (b,h): S_raw = Yq_h @ Wk_h^T via MFMA (K=768), scale, softmax.
// 512 threads (8 waves) for latency hiding on the 64 resident CUs; Wk read
// pre-converted bf16 from wb (identical RNE values).
// ---------------------------------------------------------------------------
__global__ __launch_bounds__(512)
void s_attn(const short* __restrict__ Y, const short* __restrict__ wb,
            const float* __restrict__ norms, const float* __restrict__ temp,
            float* __restrict__ S) {
  const int bh = blockIdx.x;
  const int b = bh >> 3, h = bh & 7;
  const int tid = threadIdx.x;
  const int lane = tid & 63, wave = tid >> 6;       // wave 0..7
  const int l15 = lane & 15, quad = lane >> 4;

  __shared__ __align__(16) float Sf[96 * 97];   // 37248 B; aliased as bf16 staging
  __shared__ float qsc[96], ksc[96];
  short* Ys = (short*)Sf;                // 96*72 shorts
  short* Ks = (short*)Sf + 96 * 72;      // 96*72 shorts

  if (tid < 96)
    qsc[tid] = temp[h] / fmaxf(sqrtf(norms[bh * 96 + tid]), EPSN);
  else if (tid < 192)
    ksc[tid - 96] = 1.0f / fmaxf(sqrtf(norms[B_ * H_ * 96 + bh * 96 + (tid - 96)]), EPSN);

  const short* yb = Y + ((size_t)b * 1536 + h * 96) * C_;
  const short* kb = wb + (size_t)(768 + h * 96) * C_;

  int dts[5], ets[5];
#pragma unroll
  for (int j = 0; j < 5; ++j) {
    const int t = j * 8 + wave;
    dts[j] = t / 6; ets[j] = t % 6;
  }

  f32x4 sc[5] = {};
  const int r0 = tid >> 3, c80 = (tid & 7) * 8;        // rows 0..63
  const int id1 = tid + 512;
  const int r1 = id1 >> 3, c81 = (id1 & 7) * 8;        // rows 64..95 (tid<256)
  for (int k0 = 0; k0 < C_; k0 += 64) {
    s16x8 yv0, kv0, yv1, kv1;
    yv0 = *(const s16x8*)(yb + (size_t)r0 * C_ + k0 + c80);
    kv0 = *(const s16x8*)(kb + (size_t)r0 * C_ + k0 + c80);
    if (tid < 256) {
      yv1 = *(const s16x8*)(yb + (size_t)r1 * C_ + k0 + c81);
      kv1 = *(const s16x8*)(kb + (size_t)r1 * C_ + k0 + c81);
    }
    __syncthreads();
    *(s16x8*)&Ys[r0 * 72 + c80] = yv0;
    *(s16x8*)&Ks[r0 * 72 + c80] = kv0;
    if (tid < 256) {
      *(s16x8*)&Ys[r1 * 72 + c81] = yv1;
      *(s16x8*)&Ks[r1 * 72 + c81] = kv1;
    }
    __syncthreads();
#pragma unroll
    for (int j = 0; j < 5; ++j) {
      const int t = j * 8 + wave;
      if (t < 36) {
#pragma unroll
        for (int kk = 0; kk < 64; kk += 32) {
          const s16x8 a  = *(const s16x8*)&Ys[(dts[j] * 16 + l15) * 72 + kk + quad * 8];
          const s16x8 bb = *(const s16x8*)&Ks[(ets[j] * 16 + l15) * 72 + kk + quad * 8];
          sc[j] = __builtin_amdgcn_mfma_f32_16x16x32_bf16(a, bb, sc[j], 0, 0, 0);
        }
      }
    }
  }
  __syncthreads();
#pragma unroll
  for (int j = 0; j < 5; ++j) {
    const int t = j * 8 + wave;
    if (t < 36) {
      const int e = ets[j] * 16 + l15;
      const float kf = ksc[e];
#pragma unroll
      for (int r = 0; r < 4; ++r) {
        const int d = dts[j] * 16 + quad * 4 + r;
        Sf[d * 97 + e] = sc[j][r] * qsc[d] * kf;
      }
    }
  }
  __syncthreads();
  float* Sb = S + (size_t)bh * (HD_ * HD_);
  for (int rr = 0; rr < 12; ++rr) {
    const int d = wave * 12 + rr;
    const float v0 = Sf[d * 97 + lane];
    const float v1 = (lane < 32) ? Sf[d * 97 + 64 + lane] : -1e30f;
    float mx = fmaxf(v0, v1);
#pragma unroll
    for (int o = 32; o > 0; o >>= 1) mx = fmaxf(mx, __shfl_xor(mx, o));
    const float e0 = __expf(v0 - mx);
    const float e1 = (lane < 32) ? __expf(v1 - mx) : 0.0f;
    float sum = e0 + e1;
#pragma unroll
    for (int o = 32; o > 0; o >>= 1) sum += __shfl_xor(sum, o);
    const float inv = 1.0f / sum;
    Sb[d * 96 + lane] = e0 * inv;
    if (lane < 32) Sb[d * 96 + 64 + lane] = e1 * inv;
  }
}

// ---------------------------------------------------------------------------
// av_gemm: AVt[b][c][h*96+d] (bf16) = sum_e attn[bh][d][e] * w_qkv[2C+h*96+e][c]
// ---------------------------------------------------------------------------
__global__ __launch_bounds__(256)
void av_gemm(const float* __restrict__ S, const float* __restrict__ w_qkv,
             short* __restrict__ AVt) {
  const int bh = blockIdx.x;
  const int b = bh >> 3, h = bh & 7;
  const int ct = blockIdx.y * 64;
  const int tid = threadIdx.x;
  __shared__ float at[96 * 97];
  __shared__ float wv[96 * 64];
  const float* Sb = S + (size_t)bh * (HD_ * HD_);
  for (int i = tid; i < 96 * 96; i += 256)
    at[(i / 96) * 97 + (i % 96)] = Sb[i];
  for (int i = tid; i < 96 * 64; i += 256) {
    const int e = i >> 6, c = i & 63;
    wv[e * 64 + c] = w_qkv[(size_t)(2 * C_ + h * 96 + e) * C_ + ct + c];
  }
  __syncthreads();
  const int d0 = (tid >> 4) * 6;
  const int c0 = (tid & 15) * 4;
  float acc[6][4] = {};
  for (int e = 0; e < 96; ++e) {
    const float4 bv = *(const float4*)&wv[e * 64 + c0];
    float aa[6];
#pragma unroll
    for (int i = 0; i < 6; ++i) aa[i] = at[(d0 + i) * 97 + e];
#pragma unroll
    for (int i = 0; i < 6; ++i) {
      acc[i][0] += aa[i] * bv.x; acc[i][1] += aa[i] * bv.y;
      acc[i][2] += aa[i] * bv.z; acc[i][3] += aa[i] * bv.w;
    }
  }
  short* AVb = AVt + (size_t)b * C_ * C_;
#pragma unroll
  for (int i = 0; i < 6; ++i)
#pragma unroll
    for (int j = 0; j < 4; ++j)
      AVb[(size_t)(ct + c0 + j) * C_ + h * 96 + d0 + i] = f2bf(acc[i][j]);
}

// ---------------------------------------------------------------------------
// gemm_xm_bf: out[z][m][n] = sum_k xb[z][m][k]*Mb[z][n][k] + bias[n].
// 2-phase double-buffered gld16 pipeline, XCD-swizzled grid.
// ---------------------------------------------------------------------------
__global__ __launch_bounds__(256)
void gemm_xm_bf(const short* __restrict__ xb, const short* __restrict__ Mb,
                const float* __restrict__ bias, float* __restrict__ out) {
  const int f = blockIdx.x;
  const int xcd = f & 7;
  const int t = f >> 3;           // 0..191
  const int j6 = t % 6;           // n-block (fast within XCD)
  const int sdiv = t / 6;         // 0..31
  const int s = xcd + 8 * sdiv;   // 0..255 (m-slice id)
  const int z = s >> 5;
  const int n0 = j6 * 128;
  const int m0 = (s & 31) * 128;
  const int tid = threadIdx.x;
  const int lane = tid & 63;
  const int wave = tid >> 6;
  const int l15 = lane & 15;
  const int quad = lane >> 4;
  const int wm = wave & 1;
  const int wn = wave >> 1;

  __shared__ __align__(16) short As[2][128 * 32];
  __shared__ __align__(16) short Bs[2][128 * 32];

  const short* asrc[2]; const short* bsrc[2];
  int doff[2];
#pragma unroll
  for (int cc = 0; cc < 2; ++cc) {
    const int P = wave * 1024 + cc * 512 + lane * 8;
    const int L = swz(P);
    const int row = L >> 5, col = L & 31;
    asrc[cc] = xb + ((size_t)z * N_ + m0 + row) * C_ + col;
    bsrc[cc] = Mb + (size_t)z * C_ * C_ + (size_t)(n0 + row) * C_ + col;
    doff[cc] = wave * 1024 + cc * 512;
  }

  f32x4 acc[4][4] = {};

#pragma unroll
  for (int cc = 0; cc < 2; ++cc) {
    gld16(asrc[cc], &As[0][doff[cc]]);
    gld16(bsrc[cc], &Bs[0][doff[cc]]);
  }
  __syncthreads();
  int cur = 0;
  for (int k0 = 0; k0 < C_; k0 += 32) {
    const int nx = k0 + 32;
    if (nx < C_) {
#pragma unroll
      for (int cc = 0; cc < 2; ++cc) {
        gld16(asrc[cc] + nx, &As[cur ^ 1][doff[cc]]);
        gld16(bsrc[cc] + nx, &Bs[cur ^ 1][doff[cc]]);
      }
    }
    s16x8 af[4];
#pragma unroll
    for (int mi = 0; mi < 4; ++mi)
      af[mi] = *(const s16x8*)&As[cur][swz((wm * 64 + mi * 16 + l15) * 32 + quad * 8)];
#pragma unroll
    for (int ni = 0; ni < 4; ++ni) {
      const s16x8 bf = *(const s16x8*)&Bs[cur][swz((wn * 64 + ni * 16 + l15) * 32 + quad * 8)];
#pragma unroll
      for (int mi = 0; mi < 4; ++mi)
        acc[mi][ni] = __builtin_amdgcn_mfma_f32_16x16x32_bf16(af[mi], bf, acc[mi][ni], 0, 0, 0);
    }
    __syncthreads();
    cur ^= 1;
  }

  float bv[4];
#pragma unroll
  for (int ni = 0; ni < 4; ++ni) bv[ni] = bias[n0 + wn * 64 + ni * 16 + l15];
#pragma unroll
  for (int mi = 0; mi < 4; ++mi) {
    const int m = m0 + wm * 64 + mi * 16 + quad * 4;
#pragma unroll
    for (int ni = 0; ni < 4; ++ni) {
      const int n = n0 + wn * 64 + ni * 16 + l15;
      float* dst = out + ((size_t)z * N_ + m) * C_ + n;
#pragma unroll
      for (int r = 0; r < 4; ++r)
        dst[(size_t)r * C_] = acc[mi][ni][r] + bv[ni];
    }
  }
}

// ---------------------------------------------------------------------------
// gemm_xm_f32: legacy fp32-x variant (tier-3 fallback).
// ---------------------------------------------------------------------------
__global__ __launch_bounds__(256)
void gemm_xm_f32(const float* __restrict__ x, const short* __restrict__ Mb,
                 const float* __restrict__ bias, float* __restrict__ out) {
  const int f = blockIdx.x;
  const int xcd = f & 7;
  const int t = f >> 3;
  const int j6 = t % 6;
  const int sdiv = t / 6;
  const int s = xcd + 8 * sdiv;
  const int z = s >> 5;
  const int n0 = j6 * 128;
  const int m0 = (s & 31) * 128;
  const int tid = threadIdx.x;
  const int lane = tid & 63;
  const int wave = tid >> 6;
  const int l15 = lane & 15;
  const int quad = lane >> 4;
  const int wm = wave & 1;
  const int wn = wave >> 1;

  __shared__ __align__(16) short As[128 * 40];
  __shared__ __align__(16) short Bs[128 * 40];

  const int ar = tid >> 1;
  const int ak = (tid & 1) * 16;
  const float* xp = x + ((size_t)z * N_ + m0 + ar) * C_ + ak;
  const short* mp = Mb + (size_t)z * C_ * C_ + (size_t)(n0 + ar) * C_ + ak;

  f32x4 acc[4][4] = {};

  for (int k0 = 0; k0 < C_; k0 += 32) {
    const float4 a0 = *(const float4*)(xp + k0 + 0);
    const float4 a1 = *(const float4*)(xp + k0 + 4);
    const float4 a2 = *(const float4*)(xp + k0 + 8);
    const float4 a3 = *(const float4*)(xp + k0 + 12);
    const s16x8 b0 = *(const s16x8*)(mp + k0 + 0);
    const s16x8 b1 = *(const s16x8*)(mp + k0 + 8);
    __syncthreads();
    *(s16x8*)&As[ar * 40 + ak]     = pack8(a0, a1);
    *(s16x8*)&As[ar * 40 + ak + 8] = pack8(a2, a3);
    *(s16x8*)&Bs[ar * 40 + ak]     = b0;
    *(s16x8*)&Bs[ar * 40 + ak + 8] = b1;
    __syncthreads();
    s16x8 af[4];
#pragma unroll
    for (int mi = 0; mi < 4; ++mi)
      af[mi] = *(const s16x8*)&As[(wm * 64 + mi * 16 + l15) * 40 + quad * 8];
#pragma unroll
    for (int ni = 0; ni < 4; ++ni) {
      const s16x8 bf = *(const s16x8*)&Bs[(wn * 64 + ni * 16 + l15) * 40 + quad * 8];
#pragma unroll
      for (int mi = 0; mi < 4; ++mi)
        acc[mi][ni] = __builtin_amdgcn_mfma_f32_16x16x32_bf16(af[mi], bf, acc[mi][ni], 0, 0, 0);
    }
  }

  float bv[4];
#pragma unroll
  for (int ni = 0; ni < 4; ++ni) bv[ni] = bias[n0 + wn * 64 + ni * 16 + l15];
#pragma unroll
  for (int mi = 0; mi < 4; ++mi) {
    const int m = m0 + wm * 64 + mi * 16 + quad * 4;
#pragma unroll
    for (int ni = 0; ni < 4; ++ni) {
      const int n = n0 + wn * 64 + ni * 16 + l15;
      float* dst = out + ((size_t)z * N_ + m) * C_ + n;
#pragma unroll
      for (int r = 0; r < 4; ++r)
        dst[(size_t)r * C_] = acc[mi][ni][r] + bv[ni];
    }
  }
}

// ---------------------------------------------------------------------------
extern "C" void kernel_launch(void* const* d_in, const int* in_sizes, int n_in,
                              void* d_out, int out_size, void* d_ws, size_t ws_size,
                              hipStream_t stream) {
  const float* x      = (const float*)d_in[0];
  const float* w_qkv  = (const float*)d_in[1];
  const float* temp   = (const float*)d_in[2];
  const float* w_proj = (const float*)d_in[3];
  const float* b_proj = (const float*)d_in[4];
  float* out = (float*)d_out;

  // Fixed region (byte offsets from ws base):
  //   S     @ 0         : 2359296 B  (fp32 attn)     [s_attn .. av_gemm]
  //   norms @ 2359296   : 49152 B
  //   G/AVt @ 2408448   : 9437184 B  (bf16)
  //   Mb    @ 11845632  : 9437184 B  (bf16)          [gemm_fb(Mb) .. gemm_xm]
  //   Y     @ 21282816  : 18874368 B (bf16)          [gemm_nt_bf(Y) .. s_attn]
  //   wb    @ 11845632  : 2359296 B  (bf16 w_qkv q+k rows) [wcvt .. s_attn]
  //         (inside Mb region; written AFTER gram_red -- Gp dead -- and dead
  //          before Mb is written)
  // Tier 1: Gp @ 11845632 (44 MB, overlaps Mb+Y, dead after gram_red);
  //         xb @ 55885824 (50.3 MB).
  // Tier 2: Gp and xb both @ 40157184 (Gp dead before xcvt).
  // Tier 3: no xb; fp32 gram + fp32 final GEMM.
  char* base = (char*)d_ws;
  float* S     = (float*)base;
  float* norms = (float*)(base + 2359296);
  short* G     = (short*)(base + 2408448);
  short* AVt   = G;
  short* Mb    = (short*)(base + 11845632);
  short* Y     = (short*)(base + 21282816);
  short* wb    = (short*)(base + 11845632);

  const size_t need1 = 55885824 + 50331648;   // 106217472
  const size_t need2 = 40157184 + 50331648;   // 90488832
  const int tier = (ws_size >= need1) ? 1 : (ws_size >= need2) ? 2 : 3;

  float* Gp = (tier == 2) ? (float*)(base + 40157184) : (float*)(base + 11845632);
  short* xb = (tier == 1) ? (short*)(base + 55885824)
            : (tier == 2) ? (short*)(base + 40157184) : nullptr;

  if (tier == 1) {
    xcvt<<<3072, 256, 0, stream>>>(x, xb);
    gram_p<1><<<21 * NS_ * B_, 256, 0, stream>>>(x, xb, Gp);
  } else {
    gram_p<0><<<21 * NS_ * B_, 256, 0, stream>>>(x, xb ? xb : (const short*)G, Gp);
  }

  gram_red<<<dim3(21, B_), 256, 0, stream>>>(Gp, G);

  if (tier == 2) xcvt<<<3072, 256, 0, stream>>>(x, xb);

  // wb = bf16(w_qkv rows 0..1535); Gp dead now, Mb not yet written.
  wcvt<<<576, 256, 0, stream>>>(w_qkv, wb);

  // Y_b = wb[0:1536] @ G_b   (G symmetric -> NT form, both bf16)
  gemm_nt_bf<<<dim3(C_ / 128, 1536 / 128, B_), 256, 0, stream>>>(
      wb, G, Y, (size_t)C_ * C_, (size_t)1536 * C_);

  row_norms<<<dim3(1536 / 4, B_), 256, 0, stream>>>(Y, w_qkv, norms);

  s_attn<<<B_ * H_, 512, 0, stream>>>(Y, wb, norms, temp, S);

  av_gemm<<<dim3(B_ * H_, C_ / 64), 256, 0, stream>>>(S, w_qkv, AVt);

  gemm_fb<<<dim3(C_ / 128, C_ / 128, B_), 256, 0, stream>>>(
      w_proj, AVt, Mb, (size_t)C_ * C_, (size_t)C_ * C_);

  if (tier == 3)
    gemm_xm_f32<<<C_ / 128 * (N_ / 128) * B_, 256, 0, stream>>>(x, Mb, b_proj, out);
  else
    gemm_xm_bf<<<C_ / 128 * (N_ / 128) * B_, 256, 0, stream>>>(xb, Mb, b_proj, out);
}

// Round 6
// 398.973 us; speedup vs baseline: 1.7218x; 1.0003x over previous
//
#include <hip/hip_runtime.h>
#include <cstdint>
#include <cstddef>

#define B_ 8
#define N_ 4096
#define C_ 768
#define H_ 8
#define HD_ 96
#define EPSN 1e-12f
#define NS_ 4          // gram split-K factor over tokens

typedef short s16x8 __attribute__((ext_vector_type(8)));   // 8 bf16 (4 VGPRs)
typedef short s16x4 __attribute__((ext_vector_type(4)));
typedef float f32x4 __attribute__((ext_vector_type(4)));   // MFMA acc

// fp32 -> bf16 (RNE) as raw short bits
static __device__ __forceinline__ short f2bf(float f) {
  unsigned u = __float_as_uint(f);
  unsigned r = (u + 0x7fff + ((u >> 16) & 1)) >> 16;
  return (short)r;
}
static __device__ __forceinline__ float bf2f(unsigned short s) {
  return __uint_as_float(((unsigned)s) << 16);
}
static __device__ __forceinline__ s16x8 pack8(const float4 a, const float4 b) {
  s16x8 r;
  r[0] = f2bf(a.x); r[1] = f2bf(a.y); r[2] = f2bf(a.z); r[3] = f2bf(a.w);
  r[4] = f2bf(b.x); r[5] = f2bf(b.y); r[6] = f2bf(b.z); r[7] = f2bf(b.w);
  return r;
}

// token-index swizzle for transposed LDS staging (gram)
#define TSW(ch, t) ((t) ^ ((((ch) >> 2) & 7) << 3))

// XOR swizzle for linear [128][32]-short LDS tiles staged by global_load_lds:
// involution on short offsets; XORs bits 3-4 (16B slot) with bits 7-8 (row
// bits 2-3) -> stride-32 column-slice ds_read_b128 is 2-way on banks (free).
static __device__ __forceinline__ int swz(int s) {
  return s ^ (((s >> 7) & 3) << 3);
}

// async global->LDS, 16B per lane. LDS dest = wave-uniform base + lane*16.
static __device__ __forceinline__ void gld16(const short* g, short* l) {
  __builtin_amdgcn_global_load_lds(
      (const __attribute__((address_space(1))) void*)g,
      (__attribute__((address_space(3))) void*)l, 16, 0, 0);
}

// ---------------------------------------------------------------------------
// xcvt: xb = bf16(x), one-time RNE conversion (identical f2bf as consumers).
// ---------------------------------------------------------------------------
__global__ __launch_bounds__(256)
void xcvt(const float* __restrict__ x, short* __restrict__ xb) {
  const int n8 = (B_ * N_ * C_) / 8;
  for (int i = blockIdx.x * 256 + threadIdx.x; i < n8; i += gridDim.x * 256) {
    const float4 a = *(const float4*)(x + (size_t)i * 8);
    const float4 b = *(const float4*)(x + (size_t)i * 8 + 4);
    *(s16x8*)(xb + (size_t)i * 8) = pack8(a, b);
  }
}

// ---------------------------------------------------------------------------
// wcvt: wb = bf16(w_qkv rows 0..1535)  (q+k blocks; v stays fp32 for av_gemm)
// ---------------------------------------------------------------------------
__global__ __launch_bounds__(256)
void wcvt(const float* __restrict__ w, short* __restrict__ wb) {
  const int i = blockIdx.x * 256 + threadIdx.x;     // 147456 = 1536*768/8
  const float4 a = *(const float4*)(w + (size_t)i * 8);
  const float4 b = *(const float4*)(w + (size_t)i * 8 + 4);
  *(s16x8*)(wb + (size_t)i * 8) = pack8(a, b);
}

// ---------------------------------------------------------------------------
// gram_p: partial Gram, split-K over tokens, XCD-swizzled 1D grid (672).
// BF=1: bf16 xb input; BF=0: fp32 fallback. 2 barriers per K-step.
// ---------------------------------------------------------------------------
template<int BF>
__global__ __launch_bounds__(256)
void gram_p(const float* __restrict__ x, const short* __restrict__ xb,
            float* __restrict__ Gp) {
  const int f = blockIdx.x;
  const int xcd = f & 7;
  const int t = f >> 3;            // 0..83
  const int pair = t % 21;
  const int cdiv = t / 21;         // 0..3
  const int c = xcd + 8 * cdiv;    // 0..31
  const int split = c & 3;
  const int b = c >> 2;

  int rem = pair, ti = 0;
#pragma unroll
  for (int it = 0; it < 5; ++it)
    if (rem >= 6 - ti) { rem -= 6 - ti; ++ti; }
  const int tj = ti + rem;
  const int i0 = ti * 128, j0 = tj * 128;
  const bool diag = (ti == tj);

  const int tid = threadIdx.x;
  const int lane = tid & 63, wave = tid >> 6;
  const int l15 = lane & 15, quad = lane >> 4;
  const int wm = wave & 1, wn = wave >> 1;

  __shared__ __align__(16) short smem[2 * 128 * 72];   // 36864 B
  short* At = smem;
  short* Bt = smem + 128 * 72;

  const int tg = tid >> 4;
  const int cg = tid & 15;
  const int t0 = tg * 4;
  const int c0 = cg * 4;
  const float* xbF = x + (size_t)b * N_ * C_;
  const short* xbB = xb + (size_t)b * N_ * C_;

  f32x4 acc[4][4] = {};

  const int nbeg = split * (N_ / NS_);
  const int nend = nbeg + (N_ / NS_);
  for (int n0 = nbeg; n0 < nend; n0 += 64) {
    if (BF) {
      s16x8 la[4], lb[4];
#pragma unroll
      for (int r = 0; r < 4; ++r)
        la[r] = *(const s16x8*)(xbB + (size_t)(n0 + t0 + r) * C_ + i0 + cg * 8);
      if (!diag) {
#pragma unroll
        for (int r = 0; r < 4; ++r)
          lb[r] = *(const s16x8*)(xbB + (size_t)(n0 + t0 + r) * C_ + j0 + cg * 8);
      }
      __syncthreads();
#pragma unroll
      for (int cc = 0; cc < 8; ++cc) {
        const int ch = cg * 8 + cc;
        s16x4 v;
        v[0] = la[0][cc]; v[1] = la[1][cc]; v[2] = la[2][cc]; v[3] = la[3][cc];
        *(s16x4*)&At[ch * 72 + TSW(ch, t0)] = v;
      }
      if (!diag) {
#pragma unroll
        for (int cc = 0; cc < 8; ++cc) {
          const int ch = cg * 8 + cc;
          s16x4 v;
          v[0] = lb[0][cc]; v[1] = lb[1][cc]; v[2] = lb[2][cc]; v[3] = lb[3][cc];
          *(s16x4*)&Bt[ch * 72 + TSW(ch, t0)] = v;
        }
      }
      __syncthreads();
    } else {
      float4 la[2][4], lb[2][4];
#pragma unroll
      for (int q = 0; q < 2; ++q)
#pragma unroll
        for (int r = 0; r < 4; ++r)
          la[q][r] = *(const float4*)(xbF + (size_t)(n0 + t0 + r) * C_ + i0 + c0 + q * 64);
      if (!diag) {
#pragma unroll
        for (int q = 0; q < 2; ++q)
#pragma unroll
          for (int r = 0; r < 4; ++r)
            lb[q][r] = *(const float4*)(xbF + (size_t)(n0 + t0 + r) * C_ + j0 + c0 + q * 64);
      }
      __syncthreads();
#pragma unroll
      for (int q = 0; q < 2; ++q)
#pragma unroll
        for (int cc = 0; cc < 4; ++cc) {
          const int ch = c0 + q * 64 + cc;
          s16x4 v;
          v[0] = f2bf(((const float*)&la[q][0])[cc]);
          v[1] = f2bf(((const float*)&la[q][1])[cc]);
          v[2] = f2bf(((const float*)&la[q][2])[cc]);
          v[3] = f2bf(((const float*)&la[q][3])[cc]);
          *(s16x4*)&At[ch * 72 + TSW(ch, t0)] = v;
        }
      if (!diag) {
#pragma unroll
        for (int q = 0; q < 2; ++q)
#pragma unroll
          for (int cc = 0; cc < 4; ++cc) {
            const int ch = c0 + q * 64 + cc;
            s16x4 v;
            v[0] = f2bf(((const float*)&lb[q][0])[cc]);
            v[1] = f2bf(((const float*)&lb[q][1])[cc]);
            v[2] = f2bf(((const float*)&lb[q][2])[cc]);
            v[3] = f2bf(((const float*)&lb[q][3])[cc]);
            *(s16x4*)&Bt[ch * 72 + TSW(ch, t0)] = v;
          }
      }
      __syncthreads();
    }
    const short* Bre = diag ? At : Bt;
#pragma unroll
    for (int ks = 0; ks < 64; ks += 32) {
      s16x8 af[4], bfr[4];
#pragma unroll
      for (int mi = 0; mi < 4; ++mi) {
        const int ch = wm * 64 + mi * 16 + l15;
        af[mi] = *(const s16x8*)&At[ch * 72 + TSW(ch, ks + quad * 8)];
      }
#pragma unroll
      for (int ni = 0; ni < 4; ++ni) {
        const int ch = wn * 64 + ni * 16 + l15;
        bfr[ni] = *(const s16x8*)&Bre[ch * 72 + TSW(ch, ks + quad * 8)];
      }
#pragma unroll
      for (int ni = 0; ni < 4; ++ni)
#pragma unroll
        for (int mi = 0; mi < 4; ++mi)
          acc[mi][ni] = __builtin_amdgcn_mfma_f32_16x16x32_bf16(af[mi], bfr[ni], acc[mi][ni], 0, 0, 0);
    }
  }

  float* Gpb = Gp + (((size_t)b * 21 + pair) * NS_ + split) * (128 * 128);
#pragma unroll
  for (int mi = 0; mi < 4; ++mi)
#pragma unroll
    for (int ni = 0; ni < 4; ++ni) {
      const int ii = wm * 64 + mi * 16 + quad * 4;
      const int jj = wn * 64 + ni * 16 + l15;
#pragma unroll
      for (int r = 0; r < 4; ++r)
        Gpb[(ii + r) * 128 + jj] = acc[mi][ni][r];
    }
}

// ---------------------------------------------------------------------------
// gram_red: G tile = sum of NS_ fp32 partials -> bf16, both triangles.
// ---------------------------------------------------------------------------
__global__ __launch_bounds__(256)
void gram_red(const float* __restrict__ Gp, short* __restrict__ G) {
  const int pair = blockIdx.x;
  int rem = pair, ti = 0;
#pragma unroll
  for (int it = 0; it < 5; ++it)
    if (rem >= 6 - ti) { rem -= 6 - ti; ++ti; }
  const int tj = ti + rem;
  const int b = blockIdx.y;
  const int i0 = ti * 128, j0 = tj * 128;
  const bool diag = (ti == tj);
  const int tid = threadIdx.x;

  __shared__ short Ts[128 * 137];    // 35072 B

  const float4* P = (const float4*)(Gp + (((size_t)b * 21 + pair) * NS_) * (128 * 128));
  short* Gb = G + (size_t)b * C_ * C_;

#pragma unroll
  for (int it = 0; it < 16; ++it) {
    const int q = tid + it * 256;
    const int row = q >> 5;
    const int c4 = q & 31;
    float4 v = P[q];
    const float4 v1 = P[q + 4096];
    const float4 v2 = P[q + 8192];
    const float4 v3 = P[q + 12288];
    v.x += v1.x + v2.x + v3.x;
    v.y += v1.y + v2.y + v3.y;
    v.z += v1.z + v2.z + v3.z;
    v.w += v1.w + v2.w + v3.w;
    s16x4 sv;
    sv[0] = f2bf(v.x); sv[1] = f2bf(v.y); sv[2] = f2bf(v.z); sv[3] = f2bf(v.w);
    *(s16x4*)&Gb[(size_t)(i0 + row) * C_ + j0 + c4 * 4] = sv;
    if (!diag) {
#pragma unroll
      for (int c = 0; c < 4; ++c)
        Ts[(c4 * 4 + c) * 137 + row] = sv[c];
    }
  }
  if (!diag) {
    __syncthreads();
#pragma unroll
    for (int p = 0; p < 8; ++p) {
      const int id = tid + p * 256;
      const int j = id >> 4, cs = (id & 15) * 8;
      *(s16x8*)&Gb[(size_t)(j0 + j) * C_ + i0 + cs] = *(const s16x8*)&Ts[j * 137 + cs];
    }
  }
}

// ---------------------------------------------------------------------------
// gemm_nt_bf: Out[z][m][n] (bf16) = sum_k A[m][k] * Bb[z][n][k], both bf16.
// Counted-vmcnt pipeline: raw s_barrier + s_waitcnt vmcnt(4) (never 0 in
// steady state) -- prefetch loads stay in flight across barriers (T3+T4).
// ---------------------------------------------------------------------------
__global__ __launch_bounds__(256)
void gemm_nt_bf(const short* __restrict__ A, const short* __restrict__ Bb,
                short* __restrict__ Out, size_t sB, size_t sO) {
  const int z = blockIdx.z;
  const int n0 = blockIdx.x * 128;
  const int m0 = blockIdx.y * 128;
  const int tid = threadIdx.x;
  const int lane = tid & 63, wave = tid >> 6;
  const int l15 = lane & 15, quad = lane >> 4;
  const int wm = wave & 1, wn = wave >> 1;

  __shared__ __align__(16) short As[2][128 * 32];
  __shared__ __align__(16) short Bs[2][128 * 32];

  const short* asrc[2]; const short* bsrc[2];
  int doff[2];
#pragma unroll
  for (int cc = 0; cc < 2; ++cc) {
    const int P = wave * 1024 + cc * 512 + lane * 8;
    const int L = swz(P);
    const int row = L >> 5, col = L & 31;
    asrc[cc] = A + (size_t)(m0 + row) * C_ + col;
    bsrc[cc] = Bb + (size_t)z * sB + (size_t)(n0 + row) * C_ + col;
    doff[cc] = wave * 1024 + cc * 512;
  }

  f32x4 acc[4][4] = {};

  // prologue: stage tiles 0 (buf0) and 1 (buf1) -> 8 vmem outstanding/wave
#pragma unroll
  for (int cc = 0; cc < 2; ++cc) {
    gld16(asrc[cc], &As[0][doff[cc]]);
    gld16(bsrc[cc], &Bs[0][doff[cc]]);
  }
#pragma unroll
  for (int cc = 0; cc < 2; ++cc) {
    gld16(asrc[cc] + 32, &As[1][doff[cc]]);
    gld16(bsrc[cc] + 32, &Bs[1][doff[cc]]);
  }

  int cur = 0;
  const int NT = C_ / 32;                 // 24
  for (int t = 0; t < NT; ++t) {
    if (t < NT - 1) asm volatile("s_waitcnt vmcnt(4)" ::: "memory");
    else            asm volatile("s_waitcnt vmcnt(0)" ::: "memory");
    __builtin_amdgcn_sched_barrier(0);
    __builtin_amdgcn_s_barrier();         // tile t fully in LDS (all waves)
    s16x8 af[4];
#pragma unroll
    for (int mi = 0; mi < 4; ++mi)
      af[mi] = *(const s16x8*)&As[cur][swz((wm * 64 + mi * 16 + l15) * 32 + quad * 8)];
    __builtin_amdgcn_s_setprio(1);
#pragma unroll
    for (int ni = 0; ni < 4; ++ni) {
      const s16x8 bf = *(const s16x8*)&Bs[cur][swz((wn * 64 + ni * 16 + l15) * 32 + quad * 8)];
#pragma unroll
      for (int mi = 0; mi < 4; ++mi)
        acc[mi][ni] = __builtin_amdgcn_mfma_f32_16x16x32_bf16(af[mi], bf, acc[mi][ni], 0, 0, 0);
    }
    __builtin_amdgcn_s_setprio(0);
    __builtin_amdgcn_sched_barrier(0);
    __builtin_amdgcn_s_barrier();         // all waves done reading buf[cur]
    __builtin_amdgcn_sched_barrier(0);
    if (t + 2 < NT) {
      const int nx = (t + 2) * 32;
#pragma unroll
      for (int cc = 0; cc < 2; ++cc) {
        gld16(asrc[cc] + nx, &As[cur][doff[cc]]);
        gld16(bsrc[cc] + nx, &Bs[cur][doff[cc]]);
      }
    }
    cur ^= 1;
  }

  short* ob = Out + (size_t)z * sO;
#pragma unroll
  for (int mi = 0; mi < 4; ++mi) {
    const int m = m0 + wm * 64 + mi * 16 + quad * 4;
#pragma unroll
    for (int ni = 0; ni < 4; ++ni) {
      const int n = n0 + wn * 64 + ni * 16 + l15;
#pragma unroll
      for (int r = 0; r < 4; ++r)
        ob[(size_t)(m + r) * C_ + n] = f2bf(acc[mi][ni][r]);
    }
  }
}

// ---------------------------------------------------------------------------
// gemm_fb: Out[z][m][n] (bf16) = sum_k A[m][k] (fp32) * Bb[z][n][k] (bf16).
// 2-phase: B dbuf via gld16; A dbuf via reg->pack8->LDS. 1 barrier/K-step.
// (mixed reg+DMA staging -> counted vmcnt unsafe; small kernel, keep simple)
// ---------------------------------------------------------------------------
__global__ __launch_bounds__(256)
void gemm_fb(const float* __restrict__ A, const short* __restrict__ Bb,
             short* __restrict__ Out, size_t sB, size_t sO) {
  const int z = blockIdx.z;
  const int n0 = blockIdx.x * 128;
  const int m0 = blockIdx.y * 128;
  const int tid = threadIdx.x;
  const int lane = tid & 63, wave = tid >> 6;
  const int l15 = lane & 15, quad = lane >> 4;
  const int wm = wave & 1, wn = wave >> 1;

  __shared__ __align__(16) short As[2][128 * 40];
  __shared__ __align__(16) short Bs[2][128 * 32];

  const int ar = tid >> 1;
  const int ak = (tid & 1) * 16;
  const float* ap = A + (size_t)(m0 + ar) * C_ + ak;

  const short* bsrc[2];
  int doff[2];
#pragma unroll
  for (int cc = 0; cc < 2; ++cc) {
    const int P = wave * 1024 + cc * 512 + lane * 8;
    const int L = swz(P);
    bsrc[cc] = Bb + (size_t)z * sB + (size_t)(n0 + (L >> 5)) * C_ + (L & 31);
    doff[cc] = wave * 1024 + cc * 512;
  }

  f32x4 acc[4][4] = {};

  {
    const float4 a0 = *(const float4*)(ap + 0);
    const float4 a1 = *(const float4*)(ap + 4);
    const float4 a2 = *(const float4*)(ap + 8);
    const float4 a3 = *(const float4*)(ap + 12);
#pragma unroll
    for (int cc = 0; cc < 2; ++cc) gld16(bsrc[cc], &Bs[0][doff[cc]]);
    *(s16x8*)&As[0][ar * 40 + ak]     = pack8(a0, a1);
    *(s16x8*)&As[0][ar * 40 + ak + 8] = pack8(a2, a3);
  }
  __syncthreads();
  int cur = 0;
  for (int k0 = 0; k0 < C_; k0 += 32) {
    const int nx = k0 + 32;
    float4 a0, a1, a2, a3;
    if (nx < C_) {
      a0 = *(const float4*)(ap + nx + 0);
      a1 = *(const float4*)(ap + nx + 4);
      a2 = *(const float4*)(ap + nx + 8);
      a3 = *(const float4*)(ap + nx + 12);
#pragma unroll
      for (int cc = 0; cc < 2; ++cc) gld16(bsrc[cc] + nx, &Bs[cur ^ 1][doff[cc]]);
    }
    s16x8 af[4];
#pragma unroll
    for (int mi = 0; mi < 4; ++mi)
      af[mi] = *(const s16x8*)&As[cur][(wm * 64 + mi * 16 + l15) * 40 + quad * 8];
#pragma unroll
    for (int ni = 0; ni < 4; ++ni) {
      const s16x8 bf = *(const s16x8*)&Bs[cur][swz((wn * 64 + ni * 16 + l15) * 32 + quad * 8)];
#pragma unroll
      for (int mi = 0; mi < 4; ++mi)
        acc[mi][ni] = __builtin_amdgcn_mfma_f32_16x16x32_bf16(af[mi], bf, acc[mi][ni], 0, 0, 0);
    }
    if (nx < C_) {
      *(s16x8*)&As[cur ^ 1][ar * 40 + ak]     = pack8(a0, a1);
      *(s16x8*)&As[cur ^ 1][ar * 40 + ak + 8] = pack8(a2, a3);
    }
    __syncthreads();
    cur ^= 1;
  }

  short* ob = Out + (size_t)z * sO;
#pragma unroll
  for (int mi = 0; mi < 4; ++mi) {
    const int m = m0 + wm * 64 + mi * 16 + quad * 4;
#pragma unroll
    for (int ni = 0; ni < 4; ++ni) {
      const int n = n0 + wn * 64 + ni * 16 + l15;
#pragma unroll
      for (int r = 0; r < 4; ++r)
        ob[(size_t)(m + r) * C_ + n] = f2bf(acc[mi][ni][r]);
    }
  }
}

// ---------------------------------------------------------------------------
// row_norms: ||q_d||^2 = dot(Y[row], w_qkv[row]) since Y = W_qk G, G = X^T X.
// ---------------------------------------------------------------------------
__global__ __launch_bounds__(256)
void row_norms(const short* __restrict__ Y, const float* __restrict__ w_qkv,
               float* __restrict__ norms) {
  const int b = blockIdx.y;
  const int m = blockIdx.x * 4 + (threadIdx.x >> 6);   // 0..1535
  const int lane = threadIdx.x & 63;
  const short* y = Y + ((size_t)b * 1536 + m) * C_;
  const float* w = w_qkv + (size_t)m * C_;
  float s = 0.f;
#pragma unroll
  for (int j = 0; j < 3; ++j) {
    const int o = j * 256 + lane * 4;
    const s16x4 yv = *(const s16x4*)(y + o);
    const float4 wv = *(const float4*)(w + o);
    s += bf2f((unsigned short)yv[0]) * wv.x + bf2f((unsigned short)yv[1]) * wv.y +
         bf2f((unsigned short)yv[2]) * wv.z + bf2f((unsigned short)yv[3]) * wv.w;
  }
#pragma unroll
  for (int o = 32; o > 0; o >>= 1) s += __shfl_xor(s, o);
  if (lane == 0) {
    int idx;
    if (m < 768) idx = (b * 8 + m / 96) * 96 + (m % 96);
    else { const int mm = m - 768; idx = B_ * H_ * 96 + (b * 8 + mm / 96) * 96 + (mm % 96); }
    norms[idx] = s;
  }
}

// ---------------------------------------------------------------------------
// s_attn: per (b,h): S_raw = Yq_h @ Wk_h^T via MFMA (K=768), scale, softmax.
// 512 threads (8 waves); Wk read pre-converted bf16 from wb.
// ---------------------------------------------------------------------------
__global__ __launch_bounds__(512)
void s_attn(const short* __restrict__ Y, const short* __restrict__ wb,
            const float* __restrict__ norms, const float* __restrict__ temp,
            float* __restrict__ S) {
  const int bh = blockIdx.x;
  const int b = bh >> 3, h = bh & 7;
  const int tid = threadIdx.x;
  const int lane = tid & 63, wave = tid >> 6;       // wave 0..7
  const int l15 = lane & 15, quad = lane >> 4;

  __shared__ __align__(16) float Sf[96 * 97];   // 37248 B; aliased as bf16 staging
  __shared__ float qsc[96], ksc[96];
  short* Ys = (short*)Sf;                // 96*72 shorts
  short* Ks = (short*)Sf + 96 * 72;      // 96*72 shorts

  if (tid < 96)
    qsc[tid] = temp[h] / fmaxf(sqrtf(norms[bh * 96 + tid]), EPSN);
  else if (tid < 192)
    ksc[tid - 96] = 1.0f / fmaxf(sqrtf(norms[B_ * H_ * 96 + bh * 96 + (tid - 96)]), EPSN);

  const short* yb = Y + ((size_t)b * 1536 + h * 96) * C_;
  const short* kb = wb + (size_t)(768 + h * 96) * C_;

  int dts[5], ets[5];
#pragma unroll
  for (int j = 0; j < 5; ++j) {
    const int t = j * 8 + wave;
    dts[j] = t / 6; ets[j] = t % 6;
  }

  f32x4 sc[5] = {};
  const int r0 = tid >> 3, c80 = (tid & 7) * 8;        // rows 0..63
  const int id1 = tid + 512;
  const int r1 = id1 >> 3, c81 = (id1 & 7) * 8;        // rows 64..95 (tid<256)
  for (int k0 = 0; k0 < C_; k0 += 64) {
    s16x8 yv0, kv0, yv1, kv1;
    yv0 = *(const s16x8*)(yb + (size_t)r0 * C_ + k0 + c80);
    kv0 = *(const s16x8*)(kb + (size_t)r0 * C_ + k0 + c80);
    if (tid < 256) {
      yv1 = *(const s16x8*)(yb + (size_t)r1 * C_ + k0 + c81);
      kv1 = *(const s16x8*)(kb + (size_t)r1 * C_ + k0 + c81);
    }
    __syncthreads();
    *(s16x8*)&Ys[r0 * 72 + c80] = yv0;
    *(s16x8*)&Ks[r0 * 72 + c80] = kv0;
    if (tid < 256) {
      *(s16x8*)&Ys[r1 * 72 + c81] = yv1;
      *(s16x8*)&Ks[r1 * 72 + c81] = kv1;
    }
    __syncthreads();
#pragma unroll
    for (int j = 0; j < 5; ++j) {
      const int t = j * 8 + wave;
      if (t < 36) {
#pragma unroll
        for (int kk = 0; kk < 64; kk += 32) {
          const s16x8 a  = *(const s16x8*)&Ys[(dts[j] * 16 + l15) * 72 + kk + quad * 8];
          const s16x8 bb = *(const s16x8*)&Ks[(ets[j] * 16 + l15) * 72 + kk + quad * 8];
          sc[j] = __builtin_amdgcn_mfma_f32_16x16x32_bf16(a, bb, sc[j], 0, 0, 0);
        }
      }
    }
  }
  __syncthreads();
#pragma unroll
  for (int j = 0; j < 5; ++j) {
    const int t = j * 8 + wave;
    if (t < 36) {
      const int e = ets[j] * 16 + l15;
      const float kf = ksc[e];
#pragma unroll
      for (int r = 0; r < 4; ++r) {
        const int d = dts[j] * 16 + quad * 4 + r;
        Sf[d * 97 + e] = sc[j][r] * qsc[d] * kf;
      }
    }
  }
  __syncthreads();
  float* Sb = S + (size_t)bh * (HD_ * HD_);
  for (int rr = 0; rr < 12; ++rr) {
    const int d = wave * 12 + rr;
    const float v0 = Sf[d * 97 + lane];
    const float v1 = (lane < 32) ? Sf[d * 97 + 64 + lane] : -1e30f;
    float mx = fmaxf(v0, v1);
#pragma unroll
    for (int o = 32; o > 0; o >>= 1) mx = fmaxf(mx, __shfl_xor(mx, o));
    const float e0 = __expf(v0 - mx);
    const float e1 = (lane < 32) ? __expf(v1 - mx) : 0.0f;
    float sum = e0 + e1;
#pragma unroll
    for (int o = 32; o > 0; o >>= 1) sum += __shfl_xor(sum, o);
    const float inv = 1.0f / sum;
    Sb[d * 96 + lane] = e0 * inv;
    if (lane < 32) Sb[d * 96 + 64 + lane] = e1 * inv;
  }
}

// ---------------------------------------------------------------------------
// av_gemm: AVt[b][c][h*96+d] (bf16) = sum_e attn[bh][d][e] * w_qkv[2C+h*96+e][c]
// ---------------------------------------------------------------------------
__global__ __launch_bounds__(256)
void av_gemm(const float* __restrict__ S, const float* __restrict__ w_qkv,
             short* __restrict__ AVt) {
  const int bh = blockIdx.x;
  const int b = bh >> 3, h = bh & 7;
  const int ct = blockIdx.y * 64;
  const int tid = threadIdx.x;
  __shared__ float at[96 * 97];
  __shared__ float wv[96 * 64];
  const float* Sb = S + (size_t)bh * (HD_ * HD_);
  for (int i = tid; i < 96 * 96; i += 256)
    at[(i / 96) * 97 + (i % 96)] = Sb[i];
  for (int i = tid; i < 96 * 64; i += 256) {
    const int e = i >> 6, c = i & 63;
    wv[e * 64 + c] = w_qkv[(size_t)(2 * C_ + h * 96 + e) * C_ + ct + c];
  }
  __syncthreads();
  const int d0 = (tid >> 4) * 6;
  const int c0 = (tid & 15) * 4;
  float acc[6][4] = {};
  for (int e = 0; e < 96; ++e) {
    const float4 bv = *(const float4*)&wv[e * 64 + c0];
    float aa[6];
#pragma unroll
    for (int i = 0; i < 6; ++i) aa[i] = at[(d0 + i) * 97 + e];
#pragma unroll
    for (int i = 0; i < 6; ++i) {
      acc[i][0] += aa[i] * bv.x; acc[i][1] += aa[i] * bv.y;
      acc[i][2] += aa[i] * bv.z; acc[i][3] += aa[i] * bv.w;
    }
  }
  short* AVb = AVt + (size_t)b * C_ * C_;
#pragma unroll
  for (int i = 0; i < 6; ++i)
#pragma unroll
    for (int j = 0; j < 4; ++j)
      AVb[(size_t)(ct + c0 + j) * C_ + h * 96 + d0 + i] = f2bf(acc[i][j]);
}

// ---------------------------------------------------------------------------
// gemm_xm_bf: out[z][m][n] = sum_k xb[z][m][k]*Mb[z][n][k] + bias[n].
// Counted-vmcnt pipeline (T3+T4) + setprio (T5), XCD-swizzled grid.
// ---------------------------------------------------------------------------
__global__ __launch_bounds__(256)
void gemm_xm_bf(const short* __restrict__ xb, const short* __restrict__ Mb,
                const float* __restrict__ bias, float* __restrict__ out) {
  const int f = blockIdx.x;
  const int xcd = f & 7;
  const int t6 = f >> 3;          // 0..191
  const int j6 = t6 % 6;          // n-block (fast within XCD)
  const int sdiv = t6 / 6;        // 0..31
  const int s = xcd + 8 * sdiv;   // 0..255 (m-slice id)
  const int z = s >> 5;
  const int n0 = j6 * 128;
  const int m0 = (s & 31) * 128;
  const int tid = threadIdx.x;
  const int lane = tid & 63;
  const int wave = tid >> 6;
  const int l15 = lane & 15;
  const int quad = lane >> 4;
  const int wm = wave & 1;
  const int wn = wave >> 1;

  __shared__ __align__(16) short As[2][128 * 32];
  __shared__ __align__(16) short Bs[2][128 * 32];

  const short* asrc[2]; const short* bsrc[2];
  int doff[2];
#pragma unroll
  for (int cc = 0; cc < 2; ++cc) {
    const int P = wave * 1024 + cc * 512 + lane * 8;
    const int L = swz(P);
    const int row = L >> 5, col = L & 31;
    asrc[cc] = xb + ((size_t)z * N_ + m0 + row) * C_ + col;
    bsrc[cc] = Mb + (size_t)z * C_ * C_ + (size_t)(n0 + row) * C_ + col;
    doff[cc] = wave * 1024 + cc * 512;
  }

  f32x4 acc[4][4] = {};

  // prologue: stage tiles 0 and 1 -> 8 vmem outstanding/wave
#pragma unroll
  for (int cc = 0; cc < 2; ++cc) {
    gld16(asrc[cc], &As[0][doff[cc]]);
    gld16(bsrc[cc], &Bs[0][doff[cc]]);
  }
#pragma unroll
  for (int cc = 0; cc < 2; ++cc) {
    gld16(asrc[cc] + 32, &As[1][doff[cc]]);
    gld16(bsrc[cc] + 32, &Bs[1][doff[cc]]);
  }

  int cur = 0;
  const int NT = C_ / 32;                 // 24
  for (int t = 0; t < NT; ++t) {
    if (t < NT - 1) asm volatile("s_waitcnt vmcnt(4)" ::: "memory");
    else            asm volatile("s_waitcnt vmcnt(0)" ::: "memory");
    __builtin_amdgcn_sched_barrier(0);
    __builtin_amdgcn_s_barrier();         // tile t fully in LDS (all waves)
    s16x8 af[4];
#pragma unroll
    for (int mi = 0; mi < 4; ++mi)
      af[mi] = *(const s16x8*)&As[cur][swz((wm * 64 + mi * 16 + l15) * 32 + quad * 8)];
    __builtin_amdgcn_s_setprio(1);
#pragma unroll
    for (int ni = 0; ni < 4; ++ni) {
      const s16x8 bf = *(const s16x8*)&Bs[cur][swz((wn * 64 + ni * 16 + l15) * 32 + quad * 8)];
#pragma unroll
      for (int mi = 0; mi < 4; ++mi)
        acc[mi][ni] = __builtin_amdgcn_mfma_f32_16x16x32_bf16(af[mi], bf, acc[mi][ni], 0, 0, 0);
    }
    __builtin_amdgcn_s_setprio(0);
    __builtin_amdgcn_sched_barrier(0);
    __builtin_amdgcn_s_barrier();         // all waves done reading buf[cur]
    __builtin_amdgcn_sched_barrier(0);
    if (t + 2 < NT) {
      const int nx = (t + 2) * 32;
#pragma unroll
      for (int cc = 0; cc < 2; ++cc) {
        gld16(asrc[cc] + nx, &As[cur][doff[cc]]);
        gld16(bsrc[cc] + nx, &Bs[cur][doff[cc]]);
      }
    }
    cur ^= 1;
  }

  float bv[4];
#pragma unroll
  for (int ni = 0; ni < 4; ++ni) bv[ni] = bias[n0 + wn * 64 + ni * 16 + l15];
#pragma unroll
  for (int mi = 0; mi < 4; ++mi) {
    const int m = m0 + wm * 64 + mi * 16 + quad * 4;
#pragma unroll
    for (int ni = 0; ni < 4; ++ni) {
      const int n = n0 + wn * 64 + ni * 16 + l15;
      float* dst = out + ((size_t)z * N_ + m) * C_ + n;
#pragma unroll
      for (int r = 0; r < 4; ++r)
        dst[(size_t)r * C_] = acc[mi][ni][r] + bv[ni];
    }
  }
}

// ---------------------------------------------------------------------------
// gemm_xm_f32: legacy fp32-x variant (tier-3 fallback).
// ---------------------------------------------------------------------------
__global__ __launch_bounds__(256)
void gemm_xm_f32(const float* __restrict__ x, const short* __restrict__ Mb,
                 const float* __restrict__ bias, float* __restrict__ out) {
  const int f = blockIdx.x;
  const int xcd = f & 7;
  const int t = f >> 3;
  const int j6 = t % 6;
  const int sdiv = t / 6;
  const int s = xcd + 8 * sdiv;
  const int z = s >> 5;
  const int n0 = j6 * 128;
  const int m0 = (s & 31) * 128;
  const int tid = threadIdx.x;
  const int lane = tid & 63;
  const int wave = tid >> 6;
  const int l15 = lane & 15;
  const int quad = lane >> 4;
  const int wm = wave & 1;
  const int wn = wave >> 1;

  __shared__ __align__(16) short As[128 * 40];
  __shared__ __align__(16) short Bs[128 * 40];

  const int ar = tid >> 1;
  const int ak = (tid & 1) * 16;
  const float* xp = x + ((size_t)z * N_ + m0 + ar) * C_ + ak;
  const short* mp = Mb + (size_t)z * C_ * C_ + (size_t)(n0 + ar) * C_ + ak;

  f32x4 acc[4][4] = {};

  for (int k0 = 0; k0 < C_; k0 += 32) {
    const float4 a0 = *(const float4*)(xp + k0 + 0);
    const float4 a1 = *(const float4*)(xp + k0 + 4);
    const float4 a2 = *(const float4*)(xp + k0 + 8);
    const float4 a3 = *(const float4*)(xp + k0 + 12);
    const s16x8 b0 = *(const s16x8*)(mp + k0 + 0);
    const s16x8 b1 = *(const s16x8*)(mp + k0 + 8);
    __syncthreads();
    *(s16x8*)&As[ar * 40 + ak]     = pack8(a0, a1);
    *(s16x8*)&As[ar * 40 + ak + 8] = pack8(a2, a3);
    *(s16x8*)&Bs[ar * 40 + ak]     = b0;
    *(s16x8*)&Bs[ar * 40 + ak + 8] = b1;
    __syncthreads();
    s16x8 af[4];
#pragma unroll
    for (int mi = 0; mi < 4; ++mi)
      af[mi] = *(const s16x8*)&As[(wm * 64 + mi * 16 + l15) * 40 + quad * 8];
#pragma unroll
    for (int ni = 0; ni < 4; ++ni) {
      const s16x8 bf = *(const s16x8*)&Bs[(wn * 64 + ni * 16 + l15) * 40 + quad * 8];
#pragma unroll
      for (int mi = 0; mi < 4; ++mi)
        acc[mi][ni] = __builtin_amdgcn_mfma_f32_16x16x32_bf16(af[mi], bf, acc[mi][ni], 0, 0, 0);
    }
  }

  float bv[4];
#pragma unroll
  for (int ni = 0; ni < 4; ++ni) bv[ni] = bias[n0 + wn * 64 + ni * 16 + l15];
#pragma unroll
  for (int mi = 0; mi < 4; ++mi) {
    const int m = m0 + wm * 64 + mi * 16 + quad * 4;
#pragma unroll
    for (int ni = 0; ni < 4; ++ni) {
      const int n = n0 + wn * 64 + ni * 16 + l15;
      float* dst = out + ((size_t)z * N_ + m) * C_ + n;
#pragma unroll
      for (int r = 0; r < 4; ++r)
        dst[(size_t)r * C_] = acc[mi][ni][r] + bv[ni];
    }
  }
}

// ---------------------------------------------------------------------------
extern "C" void kernel_launch(void* const* d_in, const int* in_sizes, int n_in,
                              void* d_out, int out_size, void* d_ws, size_t ws_size,
                              hipStream_t stream) {
  const float* x      = (const float*)d_in[0];
  const float* w_qkv  = (const float*)d_in[1];
  const float* temp   = (const float*)d_in[2];
  const float* w_proj = (const float*)d_in[3];
  const float* b_proj = (const float*)d_in[4];
  float* out = (float*)d_out;

  // Fixed region (byte offsets from ws base):
  //   S     @ 0         : 2359296 B  (fp32 attn)     [s_attn .. av_gemm]
  //   norms @ 2359296   : 49152 B
  //   G/AVt @ 2408448   : 9437184 B  (bf16)
  //   Mb    @ 11845632  : 9437184 B  (bf16)          [gemm_fb(Mb) .. gemm_xm]
  //   Y     @ 21282816  : 18874368 B (bf16)          [gemm_nt_bf(Y) .. s_attn]
  //   wb    @ 11845632  : 2359296 B  (bf16 w_qkv q+k rows) [wcvt .. s_attn]
  //         (inside Mb region; written AFTER gram_red -- Gp dead -- and dead
  //          before Mb is written)
  // Tier 1: Gp @ 11845632 (44 MB, overlaps Mb+Y, dead after gram_red);
  //         xb @ 55885824 (50.3 MB).
  // Tier 2: Gp and xb both @ 40157184 (Gp dead before xcvt).
  // Tier 3: no xb; fp32 gram + fp32 final GEMM.
  char* base = (char*)d_ws;
  float* S     = (float*)base;
  float* norms = (float*)(base + 2359296);
  short* G     = (short*)(base + 2408448);
  short* AVt   = G;
  short* Mb    = (short*)(base + 11845632);
  short* Y     = (short*)(base + 21282816);
  short* wb    = (short*)(base + 11845632);

  const size_t need1 = 55885824 + 50331648;   // 106217472
  const size_t need2 = 40157184 + 50331648;   // 90488832
  const int tier = (ws_size >= need1) ? 1 : (ws_size >= need2) ? 2 : 3;

  float* Gp = (tier == 2) ? (float*)(base + 40157184) : (float*)(base + 11845632);
  short* xb = (tier == 1) ? (short*)(base + 55885824)
            : (tier == 2) ? (short*)(base + 40157184) : nullptr;

  if (tier == 1) {
    xcvt<<<3072, 256, 0, stream>>>(x, xb);
    gram_p<1><<<21 * NS_ * B_, 256, 0, stream>>>(x, xb, Gp);
  } else {
    gram_p<0><<<21 * NS_ * B_, 256, 0, stream>>>(x, xb ? xb : (const short*)G, Gp);
  }

  gram_red<<<dim3(21, B_), 256, 0, stream>>>(Gp, G);

  if (tier == 2) xcvt<<<3072, 256, 0, stream>>>(x, xb);

  // wb = bf16(w_qkv rows 0..1535); Gp dead now, Mb not yet written.
  wcvt<<<576, 256, 0, stream>>>(w_qkv, wb);

  // Y_b = wb[0:1536] @ G_b   (G symmetric -> NT form, both bf16)
  gemm_nt_bf<<<dim3(C_ / 128, 1536 / 128, B_), 256, 0, stream>>>(
      wb, G, Y, (size_t)C_ * C_, (size_t)1536 * C_);

  row_norms<<<dim3(1536 / 4, B_), 256, 0, stream>>>(Y, w_qkv, norms);

  s_attn<<<B_ * H_, 512, 0, stream>>>(Y, wb, norms, temp, S);

  av_gemm<<<dim3(B_ * H_, C_ / 64), 256, 0, stream>>>(S, w_qkv, AVt);

  gemm_fb<<<dim3(C_ / 128, C_ / 128, B_), 256, 0, stream>>>(
      w_proj, AVt, Mb, (size_t)C_ * C_, (size_t)C_ * C_);

  if (tier == 3)
    gemm_xm_f32<<<C_ / 128 * (N_ / 128) * B_, 256, 0, stream>>>(x, Mb, b_proj, out);
  else
    gemm_xm_bf<<<C_ / 128 * (N_ / 128) * B_, 256, 0, stream>>>(xb, Mb, b_proj, out);
}